// Round 7
// baseline (699.363 us; speedup 1.0000x reference)
//
#include <hip/hip_runtime.h>
#include <math.h>

#define LRELU_SLOPE 0.2f

typedef __attribute__((ext_vector_type(8))) short bf16x8;
typedef __attribute__((ext_vector_type(4))) float f32x4;
typedef __attribute__((ext_vector_type(2))) float f32x2;

// ---------------- packed f32 VOP3P (CDNA full-rate; compiler won't auto-emit) ----------------
__device__ __forceinline__ f32x2 pk_add(f32x2 a, f32x2 b) {
  f32x2 d; asm("v_pk_add_f32 %0, %1, %2" : "=v"(d) : "v"(a), "v"(b)); return d;
}
__device__ __forceinline__ f32x2 pk_mul(f32x2 a, f32x2 b) {
  f32x2 d; asm("v_pk_mul_f32 %0, %1, %2" : "=v"(d) : "v"(a), "v"(b)); return d;
}
__device__ __forceinline__ f32x2 pk_fma(f32x2 a, f32x2 b, f32x2 c) {
  f32x2 d; asm("v_pk_fma_f32 %0, %1, %2, %3" : "=v"(d) : "v"(a), "v"(b), "v"(c)); return d;
}
__device__ __forceinline__ float bperm(int addr, float v) {
  return __int_as_float(__builtin_amdgcn_ds_bpermute(addr, __float_as_int(v)));
}

// ---------------- f32 <-> bf16 helpers ----------------
__device__ __forceinline__ unsigned short f2bf(float f) {
  unsigned u = __float_as_uint(f);
  return (unsigned short)((u + 0x7FFFu + ((u >> 16) & 1u)) >> 16);
}
// packed u32 (two bf16) -> f32x2
__device__ __forceinline__ f32x2 bf2x2(unsigned p) {
  f32x2 r;
  r.x = __uint_as_float(p << 16);
  r.y = __uint_as_float(p & 0xffff0000u);
  return r;
}

__global__ void cvt_bf16(const float* __restrict__ in, unsigned short* __restrict__ out, int n4) {
  int i = blockIdx.x * blockDim.x + threadIdx.x;
  if (i >= n4) return;
  float4 v = *(const float4*)(in + (size_t)i * 4);
  ushort4 o;
  o.x = f2bf(v.x); o.y = f2bf(v.y); o.z = f2bf(v.z); o.w = f2bf(v.w);
  *(ushort4*)(out + (size_t)i * 4) = o;
}

// two weight mats W[K][N] f32 -> Wt[N][K] bf16, side = blockIdx.y
__global__ void wt_cvt2(const float* __restrict__ W0, const float* __restrict__ W1,
                        unsigned short* __restrict__ Wt0, unsigned short* __restrict__ Wt1,
                        int K, int N) {
  const float* W = blockIdx.y ? W1 : W0;
  unsigned short* Wt = blockIdx.y ? Wt1 : Wt0;
  int i = blockIdx.x * blockDim.x + threadIdx.x;
  int k8s = K / 8;
  int n = i / k8s, k8 = i - n * k8s;
  if (n >= N) return;
  unsigned short tmp[8];
#pragma unroll
  for (int j = 0; j < 8; ++j) tmp[j] = f2bf(W[(size_t)(k8 * 8 + j) * N + n]);
  *(bf16x8*)(Wt + (size_t)n * K + k8 * 8) = *(bf16x8*)tmp;
}

// ---------------- MFMA GEMM pair: Y{0,1}[M][N](bf16) = Xb @ Wt{0,1}^T + bias ----------------
template<int K, int RT>
__global__ __launch_bounds__(256) void gemm_mfma2(
    const unsigned short* __restrict__ Xb,
    const unsigned short* __restrict__ Wt0, const unsigned short* __restrict__ Wt1,
    const float* __restrict__ bias0, const float* __restrict__ bias1,
    unsigned short* __restrict__ Y0, unsigned short* __restrict__ Y1, int M, int N) {
  const int nblk = N >> 6;
  const int side = blockIdx.y / nblk;
  const int n0 = (blockIdx.y - side * nblk) * 64;
  const unsigned short* Wt = side ? Wt1 : Wt0;
  const float* bias = side ? bias1 : bias0;
  unsigned short* Y = side ? Y1 : Y0;

  const int t = threadIdx.x, w = t >> 6, l = t & 63;
  const int lr = l & 15, lk = l >> 4;
  const int rowBase = blockIdx.x * (RT * 64) + w * (RT * 16);

  f32x4 acc[RT][4];
#pragma unroll
  for (int rt = 0; rt < RT; ++rt)
#pragma unroll
    for (int nt = 0; nt < 4; ++nt) acc[rt][nt] = (f32x4){0.f, 0.f, 0.f, 0.f};

  const unsigned short* ap[RT];
#pragma unroll
  for (int rt = 0; rt < RT; ++rt) {
    int row = rowBase + rt * 16 + lr;
    if (row >= M) row = M - 1;
    ap[rt] = Xb + (size_t)row * K + lk * 8;
  }
  const unsigned short* bp = Wt + (size_t)(n0 + lr) * K + lk * 8;

#pragma unroll
  for (int k0 = 0; k0 < K; k0 += 32) {
    bf16x8 a[RT], b[4];
#pragma unroll
    for (int rt = 0; rt < RT; ++rt) a[rt] = *(const bf16x8*)(ap[rt] + k0);
#pragma unroll
    for (int nt = 0; nt < 4; ++nt) b[nt] = *(const bf16x8*)(bp + (size_t)nt * 16 * K + k0);
#pragma unroll
    for (int rt = 0; rt < RT; ++rt)
#pragma unroll
      for (int nt = 0; nt < 4; ++nt)
        acc[rt][nt] = __builtin_amdgcn_mfma_f32_16x16x32_bf16(a[rt], b[nt], acc[rt][nt], 0, 0, 0);
  }

#pragma unroll
  for (int nt = 0; nt < 4; ++nt) {
    float bv = bias[n0 + nt * 16 + lr];
#pragma unroll
    for (int rt = 0; rt < RT; ++rt) {
#pragma unroll
      for (int r = 0; r < 4; ++r) {
        int row = rowBase + rt * 16 + lk * 4 + r;
        if (row < M) Y[(size_t)row * N + n0 + nt * 16 + lr] = f2bf(acc[rt][nt][r] + bv);
      }
    }
  }
}

// ---------------- f32 GEMM (final linear) ----------------
template<int K, int OUT, int ROWS>
__global__ __launch_bounds__(256) void gemm_rows(const float* __restrict__ X,
    const float* __restrict__ W, const float* __restrict__ bias,
    float* __restrict__ Y, int n) {
  __shared__ float xs[ROWS][K];
  constexpr int NG = 256 / OUT;
  constexpr int RPG = ROWS / NG;
  const int row0 = blockIdx.x * ROWS;
  const int tid = threadIdx.x;
  const int col = tid % OUT;
  const int rg  = tid / OUT;
  for (int i = tid; i < ROWS * K; i += 256) {
    int r = i / K, k = i - r * K;
    int row = row0 + r;
    xs[r][k] = (row < n) ? X[(size_t)row * K + k] : 0.f;
  }
  __syncthreads();
  float acc[RPG];
#pragma unroll
  for (int r = 0; r < RPG; ++r) acc[r] = 0.f;
  for (int k = 0; k < K; ++k) {
    float w = W[(size_t)k * OUT + col];
#pragma unroll
    for (int r = 0; r < RPG; ++r) acc[r] = fmaf(xs[rg * RPG + r][k], w, acc[r]);
  }
  float bv = bias[col];
#pragma unroll
  for (int r = 0; r < RPG; ++r) {
    int row = row0 + rg * RPG + r;
    if (row < n) Y[(size_t)row * OUT + col] = acc[r] + bv;
  }
}

// ---------------- CSR build ----------------
__global__ void hist_deg(const int* __restrict__ dst, int* __restrict__ deg, int Ee) {
  int e = blockIdx.x * blockDim.x + threadIdx.x;
  if (e < Ee) atomicAdd(&deg[dst[e]], 1);
}

__global__ void scan_deg(const int* __restrict__ deg, int* __restrict__ rowptr, int n) {
  __shared__ int tot[1024];
  const int t = threadIdx.x;
  const int chunk = (n + 1023) / 1024;
  const int lo = t * chunk;
  const int hi = min(n, lo + chunk);
  int s = 0;
  for (int i = lo; i < hi; ++i) s += deg[i];
  tot[t] = s;
  __syncthreads();
  for (int off = 1; off < 1024; off <<= 1) {
    int v = 0;
    if (t >= off) v = tot[t - off];
    __syncthreads();
    if (t >= off) tot[t] += v;
    __syncthreads();
  }
  int run = (t == 0) ? 0 : tot[t - 1];
  for (int i = lo; i < hi; ++i) { rowptr[i] = run; run += deg[i]; }
  if (t == 1023) rowptr[n] = tot[1023];
}

__global__ void fill_csr(const int* __restrict__ src, const int* __restrict__ dst,
                         const int* __restrict__ rowptr, int* __restrict__ cursor,
                         int* __restrict__ csr_src, int Ee) {
  int e = blockIdx.x * blockDim.x + threadIdx.x;
  if (e >= Ee) return;
  int d = dst[e];
  int p = atomicAdd(&cursor[d], 1);
  csr_src[rowptr[d] + p] = src[e];
}

// ---------------- fused GATv2 aggregation + bias + LayerNorm ----------------
// bf16 xl/xr; 8 edge-groups of 8 lanes; lane = 8 channels (uint4 = 4 bf16-pairs).
// Packed-f32 math; clamped CSR loads (invalid edges masked via sc=-inf).
template<int Hh, bool BF16OUT>
__global__ __launch_bounds__(256) void gat_fused(
    const unsigned short* __restrict__ xlb, const unsigned short* __restrict__ xrb,
    const float* __restrict__ att,
    const int* __restrict__ rowptr, const int* __restrict__ csr_src,
    const float* __restrict__ bo, const float* __restrict__ gam,
    const float* __restrict__ bet, void* __restrict__ outp, int n) {
  const int OUT = Hh * 64;
  const int t = threadIdx.x;
  const int wv = t >> 6, lane = t & 63;
  const int grp = lane >> 3, c8 = lane & 7;
  __shared__ float red[4];
  int node, h;
  if (Hh == 4) { node = blockIdx.x; h = wv; }
  else         { node = blockIdx.x * 4 + wv; h = 0; }
  const bool active = node < n;
  const int cb = h * 64 + c8 * 8;

  // hoisted bpermute byte-addresses
  const int la = lane << 2;
  const int bp1 = la ^ 4,  bp2 = la ^ 8,   bp4 = la ^ 16;
  const int bp8 = la ^ 32, bp16 = la ^ 64, bp32 = la ^ 128;

  f32x2 xr2[4];
  int r0 = 0, r1 = 0;
  if (active) {
    uint4 p = *(const uint4*)(xrb + (size_t)node * OUT + cb);
    xr2[0] = bf2x2(p.x); xr2[1] = bf2x2(p.y); xr2[2] = bf2x2(p.z); xr2[3] = bf2x2(p.w);
    r0 = rowptr[node]; r1 = rowptr[node + 1];
  } else {
#pragma unroll
    for (int j = 0; j < 4; ++j) xr2[j] = (f32x2){0.f, 0.f};
  }
  f32x2 at2[4];
  {
    float4 a0 = *(const float4*)(att + cb);
    float4 a1 = *(const float4*)(att + cb + 4);
    at2[0] = (f32x2){a0.x, a0.y}; at2[1] = (f32x2){a0.z, a0.w};
    at2[2] = (f32x2){a1.x, a1.y}; at2[3] = (f32x2){a1.z, a1.w};
  }
  const f32x2 slope2 = {LRELU_SLOPE, LRELU_SLOPE};

  f32x2 o2[4];
#pragma unroll
  for (int j = 0; j < 4; ++j) o2[j] = (f32x2){0.f, 0.f};
  float s = 0.f;

  const int last = max(r1 - 1, 0);
  int idx0 = min(r0 + grp, last);
  uint4 vpk = *(const uint4*)(xlb + (size_t)csr_src[idx0] * OUT + cb);

  for (int base = r0; base < r1; base += 8) {
    const uint4 pc = vpk;
    const bool vld = (base + grp) < r1;
    int idxn = min(base + 8 + grp, last);
    vpk = *(const uint4*)(xlb + (size_t)csr_src[idxn] * OUT + cb);

    f32x2 vf0 = bf2x2(pc.x), vf1 = bf2x2(pc.y), vf2v = bf2x2(pc.z), vf3 = bf2x2(pc.w);
    f32x2 sc2 = {0.f, 0.f};
    f32x2 e, em;
    e = pk_add(vf0, xr2[0]); em = pk_mul(e, slope2);
    e.x = fmaxf(e.x, em.x); e.y = fmaxf(e.y, em.y);
    sc2 = pk_fma(e, at2[0], sc2);
    e = pk_add(vf1, xr2[1]); em = pk_mul(e, slope2);
    e.x = fmaxf(e.x, em.x); e.y = fmaxf(e.y, em.y);
    sc2 = pk_fma(e, at2[1], sc2);
    e = pk_add(vf2v, xr2[2]); em = pk_mul(e, slope2);
    e.x = fmaxf(e.x, em.x); e.y = fmaxf(e.y, em.y);
    sc2 = pk_fma(e, at2[2], sc2);
    e = pk_add(vf3, xr2[3]); em = pk_mul(e, slope2);
    e.x = fmaxf(e.x, em.x); e.y = fmaxf(e.y, em.y);
    sc2 = pk_fma(e, at2[3], sc2);

    float sc = sc2.x + sc2.y;
    sc += bperm(bp1, sc);
    sc += bperm(bp2, sc);
    sc += bperm(bp4, sc);
    sc = vld ? sc : -INFINITY;
    const float w = __expf(sc);
    s += w;
    const f32x2 w2 = {w, w};
    o2[0] = pk_fma(w2, vf0, o2[0]);
    o2[1] = pk_fma(w2, vf1, o2[1]);
    o2[2] = pk_fma(w2, vf2v, o2[2]);
    o2[3] = pk_fma(w2, vf3, o2[3]);
  }

  // combine the 8 edge-groups (offsets 8,16,32)
  {
    const int addrs[3] = {bp8, bp16, bp32};
#pragma unroll
    for (int a = 0; a < 3; ++a) {
#pragma unroll
      for (int j = 0; j < 4; ++j) {
        o2[j].x += bperm(addrs[a], o2[j].x);
        o2[j].y += bperm(addrs[a], o2[j].y);
      }
      s += bperm(addrs[a], s);
    }
  }

  const float inv = 1.f / (s + 1e-16f);
  const f32x2 inv2 = {inv, inv};
  f32x2 val[4];
  {
    float4 b0 = *(const float4*)(bo + cb);
    float4 b1 = *(const float4*)(bo + cb + 4);
    val[0] = pk_fma(o2[0], inv2, (f32x2){b0.x, b0.y});
    val[1] = pk_fma(o2[1], inv2, (f32x2){b0.z, b0.w});
    val[2] = pk_fma(o2[2], inv2, (f32x2){b1.x, b1.y});
    val[3] = pk_fma(o2[3], inv2, (f32x2){b1.z, b1.w});
  }

  // ---- LayerNorm over OUT channels ----
  f32x2 tt = pk_add(pk_add(val[0], val[1]), pk_add(val[2], val[3]));
  float ls = tt.x + tt.y;
  ls += bperm(bp1, ls);
  ls += bperm(bp2, ls);
  ls += bperm(bp4, ls);
  float mu;
  if (Hh == 4) {
    if (lane == 0) red[wv] = ls;
    __syncthreads();
    mu = (red[0] + red[1] + red[2] + red[3]) * (1.f / 256.f);
  } else {
    mu = ls * (1.f / 64.f);
  }
  const f32x2 nmu2 = {-mu, -mu};
  f32x2 d[4];
  f32x2 q2 = {0.f, 0.f};
#pragma unroll
  for (int j = 0; j < 4; ++j) {
    d[j] = pk_add(val[j], nmu2);
    q2 = pk_fma(d[j], d[j], q2);
  }
  float q = q2.x + q2.y;
  q += bperm(bp1, q);
  q += bperm(bp2, q);
  q += bperm(bp4, q);
  float var;
  if (Hh == 4) {
    __syncthreads();
    if (lane == 0) red[wv] = q;
    __syncthreads();
    var = (red[0] + red[1] + red[2] + red[3]) * (1.f / 256.f);
  } else {
    var = q * (1.f / 64.f);
  }
  const float rs = rsqrtf(var + 1e-5f);
  const f32x2 rs2 = {rs, rs};

  if (active && grp == 0) {
    float4 g0 = *(const float4*)(gam + cb);
    float4 g1 = *(const float4*)(gam + cb + 4);
    float4 e0 = *(const float4*)(bet + cb);
    float4 e1 = *(const float4*)(bet + cb + 4);
    f32x2 rv[4];
    rv[0] = pk_fma(pk_mul(d[0], rs2), (f32x2){g0.x, g0.y}, (f32x2){e0.x, e0.y});
    rv[1] = pk_fma(pk_mul(d[1], rs2), (f32x2){g0.z, g0.w}, (f32x2){e0.z, e0.w});
    rv[2] = pk_fma(pk_mul(d[2], rs2), (f32x2){g1.x, g1.y}, (f32x2){e1.x, e1.y});
    rv[3] = pk_fma(pk_mul(d[3], rs2), (f32x2){g1.z, g1.w}, (f32x2){e1.z, e1.w});
    if (BF16OUT) {
      unsigned short rb[8];
#pragma unroll
      for (int j = 0; j < 4; ++j) { rb[2*j] = f2bf(rv[j].x); rb[2*j+1] = f2bf(rv[j].y); }
      *(bf16x8*)((unsigned short*)outp + (size_t)node * OUT + cb) = *(bf16x8*)rb;
    } else {
      float* fo = (float*)outp + (size_t)node * OUT + cb;
      *(float4*)fo = (float4){rv[0].x, rv[0].y, rv[1].x, rv[1].y};
      *(float4*)(fo + 4) = (float4){rv[2].x, rv[2].y, rv[3].x, rv[3].y};
    }
  }
}

extern "C" void kernel_launch(void* const* d_in, const int* in_sizes, int n_in,
                              void* d_out, int out_size, void* d_ws, size_t ws_size,
                              hipStream_t stream) {
  const float* x    = (const float*)d_in[0];
  const int*   eidx = (const int*)d_in[1];
  const int Nn = in_sizes[0] / 128;
  const int Ee = in_sizes[1] / 2;
  const int* src = eidx;
  const int* dst = eidx + Ee;

  const float* W1l = (const float*)d_in[3];  const float* b1l = (const float*)d_in[4];
  const float* W1r = (const float*)d_in[5];  const float* b1r = (const float*)d_in[6];
  const float* a1  = (const float*)d_in[7];  const float* bo1 = (const float*)d_in[8];
  const float* g1  = (const float*)d_in[9];  const float* be1 = (const float*)d_in[10];
  const float* W2l = (const float*)d_in[11]; const float* b2l = (const float*)d_in[12];
  const float* W2r = (const float*)d_in[13]; const float* b2r = (const float*)d_in[14];
  const float* a2  = (const float*)d_in[15]; const float* bo2 = (const float*)d_in[16];
  const float* g2  = (const float*)d_in[17]; const float* be2 = (const float*)d_in[18];
  const float* W3l = (const float*)d_in[19]; const float* b3l = (const float*)d_in[20];
  const float* W3r = (const float*)d_in[21]; const float* b3r = (const float*)d_in[22];
  const float* a3  = (const float*)d_in[23]; const float* bo3 = (const float*)d_in[24];
  const float* g3  = (const float*)d_in[25]; const float* be3 = (const float*)d_in[26];
  const float* linW = (const float*)d_in[27]; const float* linb = (const float*)d_in[28];

  char* ws = (char*)d_ws;
  unsigned short* xl  = (unsigned short*)ws; ws += (size_t)Nn * 256 * 2;
  unsigned short* xr  = (unsigned short*)ws; ws += (size_t)Nn * 256 * 2;
  unsigned short* Xb  = (unsigned short*)ws; ws += (size_t)Nn * 256 * 2;
  float* h            = (float*)ws;          ws += (size_t)Nn * 64 * 4;
  unsigned short* Wtl = (unsigned short*)ws; ws += 256 * 256 * 2;
  unsigned short* Wtr = (unsigned short*)ws; ws += 256 * 256 * 2;
  int*   deg    = (int*)ws;    ws += (size_t)Nn * 4;
  int*   cursor = (int*)ws;    ws += (size_t)Nn * 4;
  int*   rowptr = (int*)ws;    ws += (size_t)(Nn + 1) * 4;
  int*   csr_src= (int*)ws;    ws += (size_t)Ee * 4;

  const int eblk = (Ee + 255) / 256;

  // ---------------- CSR build (by dst) ----------------
  hipMemsetAsync(deg, 0, (size_t)Nn * 4, stream);
  hipMemsetAsync(cursor, 0, (size_t)Nn * 4, stream);
  hist_deg<<<eblk, 256, 0, stream>>>(dst, deg, Ee);
  scan_deg<<<1, 1024, 0, stream>>>(deg, rowptr, Nn);
  fill_csr<<<eblk, 256, 0, stream>>>(src, dst, rowptr, cursor, csr_src, Ee);

  // ---------------- layer 1: 128 -> 4x64 ----------------
  cvt_bf16<<<(Nn * 128 / 4 + 255) / 256, 256, 0, stream>>>(x, Xb, Nn * 128 / 4);
  wt_cvt2<<<dim3((256 * 128 / 8 + 255) / 256, 2), 256, 0, stream>>>(W1l, W1r, Wtl, Wtr, 128, 256);
  gemm_mfma2<128, 4><<<dim3((Nn + 255) / 256, 8), 256, 0, stream>>>(
      Xb, Wtl, Wtr, b1l, b1r, xl, xr, Nn, 256);
  gat_fused<4, true><<<Nn, 256, 0, stream>>>(xl, xr, a1, rowptr, csr_src, bo1, g1, be1, Xb, Nn);

  // ---------------- layer 2: 256 -> 4x64 ----------------
  wt_cvt2<<<dim3((256 * 256 / 8 + 255) / 256, 2), 256, 0, stream>>>(W2l, W2r, Wtl, Wtr, 256, 256);
  gemm_mfma2<256, 4><<<dim3((Nn + 255) / 256, 8), 256, 0, stream>>>(
      Xb, Wtl, Wtr, b2l, b2r, xl, xr, Nn, 256);
  gat_fused<4, true><<<Nn, 256, 0, stream>>>(xl, xr, a2, rowptr, csr_src, bo2, g2, be2, Xb, Nn);

  // ---------------- layer 3: 256 -> 1x64 ----------------
  wt_cvt2<<<dim3((64 * 256 / 8 + 255) / 256, 2), 256, 0, stream>>>(W3l, W3r, Wtl, Wtr, 256, 64);
  gemm_mfma2<256, 1><<<dim3((Nn + 63) / 64, 2), 256, 0, stream>>>(
      Xb, Wtl, Wtr, b3l, b3r, xl, xr, Nn, 64);
  gat_fused<1, false><<<(Nn + 3) / 4, 256, 0, stream>>>(xl, xr, a3, rowptr, csr_src, bo3, g3, be3, h, Nn);

  // ---------------- final linear 64 -> 64 (f32) ----------------
  gemm_rows<64, 64, 16><<<(Nn + 15) / 16, 256, 0, stream>>>(h, linW, linb, (float*)d_out, Nn);
}

// Round 8
// 634.053 us; speedup vs baseline: 1.1030x; 1.1030x over previous
//
#include <hip/hip_runtime.h>
#include <math.h>

#define LRELU_SLOPE 0.2f
#define L2E 1.4426950408889634f

typedef __attribute__((ext_vector_type(8))) short bf16x8;
typedef __attribute__((ext_vector_type(4))) float f32x4;

__device__ __forceinline__ float fast_exp2(float x) {
  float r; asm("v_exp_f32 %0, %1" : "=v"(r) : "v"(x)); return r;
}

// ---------------- f32 <-> bf16 helpers ----------------
__device__ __forceinline__ unsigned short f2bf(float f) {
  unsigned u = __float_as_uint(f);
  return (unsigned short)((u + 0x7FFFu + ((u >> 16) & 1u)) >> 16);
}
__device__ __forceinline__ float bf2f(short b) {
  return __uint_as_float(((unsigned)(unsigned short)b) << 16);
}

__global__ void cvt_bf16(const float* __restrict__ in, unsigned short* __restrict__ out, int n4) {
  int i = blockIdx.x * blockDim.x + threadIdx.x;
  if (i >= n4) return;
  float4 v = *(const float4*)(in + (size_t)i * 4);
  ushort4 o;
  o.x = f2bf(v.x); o.y = f2bf(v.y); o.z = f2bf(v.z); o.w = f2bf(v.w);
  *(ushort4*)(out + (size_t)i * 4) = o;
}

// two weight mats W[K][N] f32 -> Wt[N][K] bf16, side = blockIdx.y
__global__ void wt_cvt2(const float* __restrict__ W0, const float* __restrict__ W1,
                        unsigned short* __restrict__ Wt0, unsigned short* __restrict__ Wt1,
                        int K, int N) {
  const float* W = blockIdx.y ? W1 : W0;
  unsigned short* Wt = blockIdx.y ? Wt1 : Wt0;
  int i = blockIdx.x * blockDim.x + threadIdx.x;
  int k8s = K / 8;
  int n = i / k8s, k8 = i - n * k8s;
  if (n >= N) return;
  unsigned short tmp[8];
#pragma unroll
  for (int j = 0; j < 8; ++j) tmp[j] = f2bf(W[(size_t)(k8 * 8 + j) * N + n]);
  *(bf16x8*)(Wt + (size_t)n * K + k8 * 8) = *(bf16x8*)tmp;
}

// ---------------- MFMA GEMM pair: Y{0,1}[M][N](bf16) = Xb @ Wt{0,1}^T + bias ----------------
template<int K, int RT>
__global__ __launch_bounds__(256) void gemm_mfma2(
    const unsigned short* __restrict__ Xb,
    const unsigned short* __restrict__ Wt0, const unsigned short* __restrict__ Wt1,
    const float* __restrict__ bias0, const float* __restrict__ bias1,
    unsigned short* __restrict__ Y0, unsigned short* __restrict__ Y1, int M, int N) {
  const int nblk = N >> 6;
  const int side = blockIdx.y / nblk;
  const int n0 = (blockIdx.y - side * nblk) * 64;
  const unsigned short* Wt = side ? Wt1 : Wt0;
  const float* bias = side ? bias1 : bias0;
  unsigned short* Y = side ? Y1 : Y0;

  const int t = threadIdx.x, w = t >> 6, l = t & 63;
  const int lr = l & 15, lk = l >> 4;
  const int rowBase = blockIdx.x * (RT * 64) + w * (RT * 16);

  f32x4 acc[RT][4];
#pragma unroll
  for (int rt = 0; rt < RT; ++rt)
#pragma unroll
    for (int nt = 0; nt < 4; ++nt) acc[rt][nt] = (f32x4){0.f, 0.f, 0.f, 0.f};

  const unsigned short* ap[RT];
#pragma unroll
  for (int rt = 0; rt < RT; ++rt) {
    int row = rowBase + rt * 16 + lr;
    if (row >= M) row = M - 1;
    ap[rt] = Xb + (size_t)row * K + lk * 8;
  }
  const unsigned short* bp = Wt + (size_t)(n0 + lr) * K + lk * 8;

#pragma unroll
  for (int k0 = 0; k0 < K; k0 += 32) {
    bf16x8 a[RT], b[4];
#pragma unroll
    for (int rt = 0; rt < RT; ++rt) a[rt] = *(const bf16x8*)(ap[rt] + k0);
#pragma unroll
    for (int nt = 0; nt < 4; ++nt) b[nt] = *(const bf16x8*)(bp + (size_t)nt * 16 * K + k0);
#pragma unroll
    for (int rt = 0; rt < RT; ++rt)
#pragma unroll
      for (int nt = 0; nt < 4; ++nt)
        acc[rt][nt] = __builtin_amdgcn_mfma_f32_16x16x32_bf16(a[rt], b[nt], acc[rt][nt], 0, 0, 0);
  }

#pragma unroll
  for (int nt = 0; nt < 4; ++nt) {
    float bv = bias[n0 + nt * 16 + lr];
#pragma unroll
    for (int rt = 0; rt < RT; ++rt) {
#pragma unroll
      for (int r = 0; r < 4; ++r) {
        int row = rowBase + rt * 16 + lk * 4 + r;
        if (row < M) Y[(size_t)row * N + n0 + nt * 16 + lr] = f2bf(acc[rt][nt][r] + bv);
      }
    }
  }
}

// ---------------- CSR build ----------------
__global__ void hist_deg(const int* __restrict__ dst, int* __restrict__ deg, int Ee) {
  int e = blockIdx.x * blockDim.x + threadIdx.x;
  if (e < Ee) atomicAdd(&deg[dst[e]], 1);
}

__global__ void scan_deg(const int* __restrict__ deg, int* __restrict__ rowptr, int n) {
  __shared__ int tot[1024];
  const int t = threadIdx.x;
  const int chunk = (n + 1023) / 1024;
  const int lo = t * chunk;
  const int hi = min(n, lo + chunk);
  int s = 0;
  for (int i = lo; i < hi; ++i) s += deg[i];
  tot[t] = s;
  __syncthreads();
  for (int off = 1; off < 1024; off <<= 1) {
    int v = 0;
    if (t >= off) v = tot[t - off];
    __syncthreads();
    if (t >= off) tot[t] += v;
    __syncthreads();
  }
  int run = (t == 0) ? 0 : tot[t - 1];
  for (int i = lo; i < hi; ++i) { rowptr[i] = run; run += deg[i]; }
  if (t == 1023) rowptr[n] = tot[1023];
}

__global__ void fill_csr(const int* __restrict__ src, const int* __restrict__ dst,
                         const int* __restrict__ rowptr, int* __restrict__ cursor,
                         int* __restrict__ csr_src, int Ee) {
  int e = blockIdx.x * blockDim.x + threadIdx.x;
  if (e >= Ee) return;
  int d = dst[e];
  int p = atomicAdd(&cursor[d], 1);
  csr_src[rowptr[d] + p] = src[e];
}

// ---------------- fused GATv2 aggregation + bias + LayerNorm (H=4, bf16 out) ----------------
// bf16 xl/xr. 8 edge-groups of 8 lanes; lane holds 8 channels.
// No-max softmax via exp2 (att pre-scaled by log2 e).
__global__ __launch_bounds__(256) void gat_fused4(
    const unsigned short* __restrict__ xlb, const unsigned short* __restrict__ xrb,
    const float* __restrict__ att,
    const int* __restrict__ rowptr, const int* __restrict__ csr_src,
    const float* __restrict__ bo, const float* __restrict__ gam,
    const float* __restrict__ bet, unsigned short* __restrict__ outp, int n) {
  const int OUT = 256;
  const int t = threadIdx.x;
  const int wv = t >> 6, lane = t & 63;
  const int grp = lane >> 3, c8 = lane & 7;
  __shared__ float red[4];
  const int node = blockIdx.x;
  const int h = wv;
  const bool active = node < n;
  const int cb = h * 64 + c8 * 8;

  float xrf[8];
  int r0 = 0, r1 = 0;
  if (active) {
    bf16x8 xv = *(const bf16x8*)(xrb + (size_t)node * OUT + cb);
#pragma unroll
    for (int i = 0; i < 8; ++i) xrf[i] = bf2f(xv[i]);
    r0 = rowptr[node];
    r1 = rowptr[node + 1];
  } else {
#pragma unroll
    for (int i = 0; i < 8; ++i) xrf[i] = 0.f;
  }
  float atf[8];
  {
    float4 a0 = *(const float4*)(att + cb);
    float4 a1 = *(const float4*)(att + cb + 4);
    atf[0] = a0.x * L2E; atf[1] = a0.y * L2E; atf[2] = a0.z * L2E; atf[3] = a0.w * L2E;
    atf[4] = a1.x * L2E; atf[5] = a1.y * L2E; atf[6] = a1.z * L2E; atf[7] = a1.w * L2E;
  }

  float s = 0.f;
  float o[8];
#pragma unroll
  for (int i = 0; i < 8; ++i) o[i] = 0.f;

  bf16x8 v = {};
  {
    int i0 = r0 + grp;
    if (i0 < r1) {
      int sn = csr_src[i0];
      v = *(const bf16x8*)(xlb + (size_t)sn * OUT + cb);
    }
  }
  bool valid = (r0 + grp) < r1;

  for (int base = r0; base < r1; base += 8) {
    const bf16x8 vc = v;
    const bool vld = valid;
    int inext = base + 8 + grp;
    valid = inext < r1;
    if (valid) {
      int sn = csr_src[inext];
      v = *(const bf16x8*)(xlb + (size_t)sn * OUT + cb);
    }
    float vf[8];
#pragma unroll
    for (int i = 0; i < 8; ++i) vf[i] = bf2f(vc[i]);
    float sc = 0.f;
#pragma unroll
    for (int i = 0; i < 8; ++i) {
      float e = vf[i] + xrf[i];
      e = fmaxf(e, LRELU_SLOPE * e);
      sc = fmaf(e, atf[i], sc);
    }
    sc += __shfl_xor(sc, 1);
    sc += __shfl_xor(sc, 2);
    sc += __shfl_xor(sc, 4);
    if (!vld) sc = -INFINITY;
    const float w = fast_exp2(sc);   // exp2(-inf)=0 for invalid
    s += w;
#pragma unroll
    for (int i = 0; i < 8; ++i) o[i] = fmaf(w, vf[i], o[i]);
  }

  // combine the 8 edge-groups
#pragma unroll
  for (int off = 8; off < 64; off <<= 1) {
#pragma unroll
    for (int i = 0; i < 8; ++i) o[i] += __shfl_xor(o[i], off);
    s += __shfl_xor(s, off);
  }

  const float inv = 1.f / (s + 1e-16f);
  float val[8];
  {
    float4 b0 = *(const float4*)(bo + cb);
    float4 b1 = *(const float4*)(bo + cb + 4);
    val[0] = fmaf(o[0], inv, b0.x); val[1] = fmaf(o[1], inv, b0.y);
    val[2] = fmaf(o[2], inv, b0.z); val[3] = fmaf(o[3], inv, b0.w);
    val[4] = fmaf(o[4], inv, b1.x); val[5] = fmaf(o[5], inv, b1.y);
    val[6] = fmaf(o[6], inv, b1.z); val[7] = fmaf(o[7], inv, b1.w);
  }

  // ---- LayerNorm over 256 channels ----
  float ls = 0.f;
#pragma unroll
  for (int i = 0; i < 8; ++i) ls += val[i];
  ls += __shfl_xor(ls, 1);
  ls += __shfl_xor(ls, 2);
  ls += __shfl_xor(ls, 4);
  if (lane == 0) red[wv] = ls;
  __syncthreads();
  float mu = (red[0] + red[1] + red[2] + red[3]) * (1.f / 256.f);
  float d[8], q = 0.f;
#pragma unroll
  for (int i = 0; i < 8; ++i) { d[i] = val[i] - mu; q = fmaf(d[i], d[i], q); }
  q += __shfl_xor(q, 1);
  q += __shfl_xor(q, 2);
  q += __shfl_xor(q, 4);
  __syncthreads();
  if (lane == 0) red[wv] = q;
  __syncthreads();
  float var = (red[0] + red[1] + red[2] + red[3]) * (1.f / 256.f);
  const float rs = rsqrtf(var + 1e-5f);

  if (active && grp == 0) {
    float4 g0 = *(const float4*)(gam + cb);
    float4 g1 = *(const float4*)(gam + cb + 4);
    float4 e0 = *(const float4*)(bet + cb);
    float4 e1 = *(const float4*)(bet + cb + 4);
    float rv[8];
    rv[0] = fmaf(d[0] * rs, g0.x, e0.x); rv[1] = fmaf(d[1] * rs, g0.y, e0.y);
    rv[2] = fmaf(d[2] * rs, g0.z, e0.z); rv[3] = fmaf(d[3] * rs, g0.w, e0.w);
    rv[4] = fmaf(d[4] * rs, g1.x, e1.x); rv[5] = fmaf(d[5] * rs, g1.y, e1.y);
    rv[6] = fmaf(d[6] * rs, g1.z, e1.z); rv[7] = fmaf(d[7] * rs, g1.w, e1.w);
    unsigned short rb[8];
#pragma unroll
    for (int i = 0; i < 8; ++i) rb[i] = f2bf(rv[i]);
    *(bf16x8*)(outp + (size_t)node * OUT + cb) = *(bf16x8*)rb;
  }
}

// ---------------- layer-3 GAT (H=1) + LayerNorm + fused final linear 64->64 ----------------
// block = 4 nodes (one per wave). Epilogue: h staged in LDS, out = h @ linW + linb.
__global__ __launch_bounds__(256) void gat1_lin(
    const unsigned short* __restrict__ xlb, const unsigned short* __restrict__ xrb,
    const float* __restrict__ att,
    const int* __restrict__ rowptr, const int* __restrict__ csr_src,
    const float* __restrict__ bo, const float* __restrict__ gam,
    const float* __restrict__ bet,
    const float* __restrict__ linW, const float* __restrict__ linb,
    float* __restrict__ outp, int n) {
  const int OUT = 64;
  const int t = threadIdx.x;
  const int wv = t >> 6, lane = t & 63;
  const int grp = lane >> 3, c8 = lane & 7;
  __shared__ float lw[64][64];
  __shared__ float hbuf[4][64];
  // stage linW (16 KB), coalesced
  for (int i = t; i < 4096; i += 256) lw[i >> 6][i & 63] = linW[i];

  const int node = blockIdx.x * 4 + wv;
  const bool active = node < n;
  const int cb = c8 * 8;

  float xrf[8];
  int r0 = 0, r1 = 0;
  if (active) {
    bf16x8 xv = *(const bf16x8*)(xrb + (size_t)node * OUT + cb);
#pragma unroll
    for (int i = 0; i < 8; ++i) xrf[i] = bf2f(xv[i]);
    r0 = rowptr[node];
    r1 = rowptr[node + 1];
  } else {
#pragma unroll
    for (int i = 0; i < 8; ++i) xrf[i] = 0.f;
  }
  float atf[8];
  {
    float4 a0 = *(const float4*)(att + cb);
    float4 a1 = *(const float4*)(att + cb + 4);
    atf[0] = a0.x * L2E; atf[1] = a0.y * L2E; atf[2] = a0.z * L2E; atf[3] = a0.w * L2E;
    atf[4] = a1.x * L2E; atf[5] = a1.y * L2E; atf[6] = a1.z * L2E; atf[7] = a1.w * L2E;
  }

  float s = 0.f;
  float o[8];
#pragma unroll
  for (int i = 0; i < 8; ++i) o[i] = 0.f;

  bf16x8 v = {};
  {
    int i0 = r0 + grp;
    if (i0 < r1) {
      int sn = csr_src[i0];
      v = *(const bf16x8*)(xlb + (size_t)sn * OUT + cb);
    }
  }
  bool valid = (r0 + grp) < r1;

  for (int base = r0; base < r1; base += 8) {
    const bf16x8 vc = v;
    const bool vld = valid;
    int inext = base + 8 + grp;
    valid = inext < r1;
    if (valid) {
      int sn = csr_src[inext];
      v = *(const bf16x8*)(xlb + (size_t)sn * OUT + cb);
    }
    float vf[8];
#pragma unroll
    for (int i = 0; i < 8; ++i) vf[i] = bf2f(vc[i]);
    float sc = 0.f;
#pragma unroll
    for (int i = 0; i < 8; ++i) {
      float e = vf[i] + xrf[i];
      e = fmaxf(e, LRELU_SLOPE * e);
      sc = fmaf(e, atf[i], sc);
    }
    sc += __shfl_xor(sc, 1);
    sc += __shfl_xor(sc, 2);
    sc += __shfl_xor(sc, 4);
    if (!vld) sc = -INFINITY;
    const float w = fast_exp2(sc);
    s += w;
#pragma unroll
    for (int i = 0; i < 8; ++i) o[i] = fmaf(w, vf[i], o[i]);
  }

#pragma unroll
  for (int off = 8; off < 64; off <<= 1) {
#pragma unroll
    for (int i = 0; i < 8; ++i) o[i] += __shfl_xor(o[i], off);
    s += __shfl_xor(s, off);
  }

  const float inv = 1.f / (s + 1e-16f);
  float val[8];
  {
    float4 b0 = *(const float4*)(bo + cb);
    float4 b1 = *(const float4*)(bo + cb + 4);
    val[0] = fmaf(o[0], inv, b0.x); val[1] = fmaf(o[1], inv, b0.y);
    val[2] = fmaf(o[2], inv, b0.z); val[3] = fmaf(o[3], inv, b0.w);
    val[4] = fmaf(o[4], inv, b1.x); val[5] = fmaf(o[5], inv, b1.y);
    val[6] = fmaf(o[6], inv, b1.z); val[7] = fmaf(o[7], inv, b1.w);
  }

  // LN over 64 channels (each 8-lane grp holds all 64)
  float ls = 0.f;
#pragma unroll
  for (int i = 0; i < 8; ++i) ls += val[i];
  ls += __shfl_xor(ls, 1);
  ls += __shfl_xor(ls, 2);
  ls += __shfl_xor(ls, 4);
  float mu = ls * (1.f / 64.f);
  float d[8], q = 0.f;
#pragma unroll
  for (int i = 0; i < 8; ++i) { d[i] = val[i] - mu; q = fmaf(d[i], d[i], q); }
  q += __shfl_xor(q, 1);
  q += __shfl_xor(q, 2);
  q += __shfl_xor(q, 4);
  float var = q * (1.f / 64.f);
  const float rs = rsqrtf(var + 1e-5f);

  // LN result -> hbuf (grp 0 covers all 64 channels)
  if (grp == 0) {
    float4 g0 = *(const float4*)(gam + cb);
    float4 g1 = *(const float4*)(gam + cb + 4);
    float4 e0 = *(const float4*)(bet + cb);
    float4 e1 = *(const float4*)(bet + cb + 4);
    float* hb = &hbuf[wv][cb];
    hb[0] = fmaf(d[0] * rs, g0.x, e0.x); hb[1] = fmaf(d[1] * rs, g0.y, e0.y);
    hb[2] = fmaf(d[2] * rs, g0.z, e0.z); hb[3] = fmaf(d[3] * rs, g0.w, e0.w);
    hb[4] = fmaf(d[4] * rs, g1.x, e1.x); hb[5] = fmaf(d[5] * rs, g1.y, e1.y);
    hb[6] = fmaf(d[6] * rs, g1.z, e1.z); hb[7] = fmaf(d[7] * rs, g1.w, e1.w);
  }
  __syncthreads();

  // out[node][lane] = linb[lane] + sum_k hbuf[wv][k] * lw[k][lane]
  float acc = linb[lane];
#pragma unroll 8
  for (int k = 0; k < 64; ++k) acc = fmaf(hbuf[wv][k], lw[k][lane], acc);
  if (active) outp[(size_t)node * 64 + lane] = acc;
}

extern "C" void kernel_launch(void* const* d_in, const int* in_sizes, int n_in,
                              void* d_out, int out_size, void* d_ws, size_t ws_size,
                              hipStream_t stream) {
  const float* x    = (const float*)d_in[0];
  const int*   eidx = (const int*)d_in[1];
  const int Nn = in_sizes[0] / 128;
  const int Ee = in_sizes[1] / 2;
  const int* src = eidx;
  const int* dst = eidx + Ee;

  const float* W1l = (const float*)d_in[3];  const float* b1l = (const float*)d_in[4];
  const float* W1r = (const float*)d_in[5];  const float* b1r = (const float*)d_in[6];
  const float* a1  = (const float*)d_in[7];  const float* bo1 = (const float*)d_in[8];
  const float* g1  = (const float*)d_in[9];  const float* be1 = (const float*)d_in[10];
  const float* W2l = (const float*)d_in[11]; const float* b2l = (const float*)d_in[12];
  const float* W2r = (const float*)d_in[13]; const float* b2r = (const float*)d_in[14];
  const float* a2  = (const float*)d_in[15]; const float* bo2 = (const float*)d_in[16];
  const float* g2  = (const float*)d_in[17]; const float* be2 = (const float*)d_in[18];
  const float* W3l = (const float*)d_in[19]; const float* b3l = (const float*)d_in[20];
  const float* W3r = (const float*)d_in[21]; const float* b3r = (const float*)d_in[22];
  const float* a3  = (const float*)d_in[23]; const float* bo3 = (const float*)d_in[24];
  const float* g3  = (const float*)d_in[25]; const float* be3 = (const float*)d_in[26];
  const float* linW = (const float*)d_in[27]; const float* linb = (const float*)d_in[28];

  char* ws = (char*)d_ws;
  unsigned short* xl  = (unsigned short*)ws; ws += (size_t)Nn * 256 * 2;
  unsigned short* xr  = (unsigned short*)ws; ws += (size_t)Nn * 256 * 2;
  unsigned short* Xb  = (unsigned short*)ws; ws += (size_t)Nn * 256 * 2;
  unsigned short* Wtl = (unsigned short*)ws; ws += 256 * 256 * 2;
  unsigned short* Wtr = (unsigned short*)ws; ws += 256 * 256 * 2;
  int*   deg    = (int*)ws;    ws += (size_t)Nn * 4;
  int*   cursor = (int*)ws;    ws += (size_t)Nn * 4;
  int*   rowptr = (int*)ws;    ws += (size_t)(Nn + 1) * 4;
  int*   csr_src= (int*)ws;    ws += (size_t)Ee * 4;

  const int eblk = (Ee + 255) / 256;

  // ---------------- CSR build (by dst) ----------------
  hipMemsetAsync(deg, 0, (size_t)Nn * 4, stream);
  hipMemsetAsync(cursor, 0, (size_t)Nn * 4, stream);
  hist_deg<<<eblk, 256, 0, stream>>>(dst, deg, Ee);
  scan_deg<<<1, 1024, 0, stream>>>(deg, rowptr, Nn);
  fill_csr<<<eblk, 256, 0, stream>>>(src, dst, rowptr, cursor, csr_src, Ee);

  // ---------------- layer 1: 128 -> 4x64 ----------------
  cvt_bf16<<<(Nn * 128 / 4 + 255) / 256, 256, 0, stream>>>(x, Xb, Nn * 128 / 4);
  wt_cvt2<<<dim3((256 * 128 / 8 + 255) / 256, 2), 256, 0, stream>>>(W1l, W1r, Wtl, Wtr, 128, 256);
  gemm_mfma2<128, 4><<<dim3((Nn + 255) / 256, 8), 256, 0, stream>>>(
      Xb, Wtl, Wtr, b1l, b1r, xl, xr, Nn, 256);
  gat_fused4<<<Nn, 256, 0, stream>>>(xl, xr, a1, rowptr, csr_src, bo1, g1, be1, Xb, Nn);

  // ---------------- layer 2: 256 -> 4x64 ----------------
  wt_cvt2<<<dim3((256 * 256 / 8 + 255) / 256, 2), 256, 0, stream>>>(W2l, W2r, Wtl, Wtr, 256, 256);
  gemm_mfma2<256, 4><<<dim3((Nn + 255) / 256, 8), 256, 0, stream>>>(
      Xb, Wtl, Wtr, b2l, b2r, xl, xr, Nn, 256);
  gat_fused4<<<Nn, 256, 0, stream>>>(xl, xr, a2, rowptr, csr_src, bo2, g2, be2, Xb, Nn);

  // ---------------- layer 3: 256 -> 1x64 + LN + final linear ----------------
  wt_cvt2<<<dim3((64 * 256 / 8 + 255) / 256, 2), 256, 0, stream>>>(W3l, W3r, Wtl, Wtr, 256, 64);
  gemm_mfma2<256, 1><<<dim3((Nn + 63) / 64, 2), 256, 0, stream>>>(
      Xb, Wtl, Wtr, b3l, b3r, xl, xr, Nn, 64);
  gat1_lin<<<(Nn + 3) / 4, 256, 0, stream>>>(xl, xr, a3, rowptr, csr_src, bo3, g3, be3,
                                             linW, linb, (float*)d_out, Nn);
}

// Round 9
// 621.536 us; speedup vs baseline: 1.1252x; 1.0201x over previous
//
#include <hip/hip_runtime.h>
#include <math.h>

#define LRELU_SLOPE 0.2f
#define L2E 1.4426950408889634f

typedef __attribute__((ext_vector_type(8))) short bf16x8;
typedef __attribute__((ext_vector_type(4))) float f32x4;
typedef __attribute__((ext_vector_type(2))) float f2;

__device__ __forceinline__ float fast_exp2(float x) {
  float r; asm("v_exp_f32 %0, %1" : "=v"(r) : "v"(x)); return r;
}

// ---------------- f32 <-> bf16 helpers ----------------
__device__ __forceinline__ unsigned short f2bf(float f) {
  unsigned u = __float_as_uint(f);
  return (unsigned short)((u + 0x7FFFu + ((u >> 16) & 1u)) >> 16);
}
__device__ __forceinline__ float bf2f(short b) {
  return __uint_as_float(((unsigned)(unsigned short)b) << 16);
}
// packed u32 (two bf16) -> f2
__device__ __forceinline__ f2 bfpair(unsigned p) {
  f2 r;
  r.x = __uint_as_float(p << 16);
  r.y = __uint_as_float(p & 0xffff0000u);
  return r;
}

__global__ void cvt_bf16(const float* __restrict__ in, unsigned short* __restrict__ out, int n4) {
  int i = blockIdx.x * blockDim.x + threadIdx.x;
  if (i >= n4) return;
  float4 v = *(const float4*)(in + (size_t)i * 4);
  ushort4 o;
  o.x = f2bf(v.x); o.y = f2bf(v.y); o.z = f2bf(v.z); o.w = f2bf(v.w);
  *(ushort4*)(out + (size_t)i * 4) = o;
}

// all six weight mats W[K][N] f32 -> Wt[N][K] bf16 in one dispatch
__global__ void wt_cvt_all(
    const float* __restrict__ W1l, const float* __restrict__ W1r,
    const float* __restrict__ W2l, const float* __restrict__ W2r,
    const float* __restrict__ W3l, const float* __restrict__ W3r,
    unsigned short* __restrict__ Wt1l, unsigned short* __restrict__ Wt1r,
    unsigned short* __restrict__ Wt2l, unsigned short* __restrict__ Wt2r,
    unsigned short* __restrict__ Wt3l, unsigned short* __restrict__ Wt3r) {
  const float* W; unsigned short* Wt; int K, N;
  switch (blockIdx.y) {
    case 0: W = W1l; Wt = Wt1l; K = 128; N = 256; break;
    case 1: W = W1r; Wt = Wt1r; K = 128; N = 256; break;
    case 2: W = W2l; Wt = Wt2l; K = 256; N = 256; break;
    case 3: W = W2r; Wt = Wt2r; K = 256; N = 256; break;
    case 4: W = W3l; Wt = Wt3l; K = 256; N = 64;  break;
    default: W = W3r; Wt = Wt3r; K = 256; N = 64; break;
  }
  int i = blockIdx.x * blockDim.x + threadIdx.x;
  int k8s = K / 8;
  int n = i / k8s, k8 = i - n * k8s;
  if (n >= N) return;
  unsigned short tmp[8];
#pragma unroll
  for (int j = 0; j < 8; ++j) tmp[j] = f2bf(W[(size_t)(k8 * 8 + j) * N + n]);
  *(bf16x8*)(Wt + (size_t)n * K + k8 * 8) = *(bf16x8*)tmp;
}

// ---------------- MFMA GEMM pair: Y{0,1}[M][N](bf16) = Xb @ Wt{0,1}^T + bias ----------------
template<int K, int RT>
__global__ __launch_bounds__(256) void gemm_mfma2(
    const unsigned short* __restrict__ Xb,
    const unsigned short* __restrict__ Wt0, const unsigned short* __restrict__ Wt1,
    const float* __restrict__ bias0, const float* __restrict__ bias1,
    unsigned short* __restrict__ Y0, unsigned short* __restrict__ Y1, int M, int N) {
  const int nblk = N >> 6;
  const int side = blockIdx.y / nblk;
  const int n0 = (blockIdx.y - side * nblk) * 64;
  const unsigned short* Wt = side ? Wt1 : Wt0;
  const float* bias = side ? bias1 : bias0;
  unsigned short* Y = side ? Y1 : Y0;

  const int t = threadIdx.x, w = t >> 6, l = t & 63;
  const int lr = l & 15, lk = l >> 4;
  const int rowBase = blockIdx.x * (RT * 64) + w * (RT * 16);

  f32x4 acc[RT][4];
#pragma unroll
  for (int rt = 0; rt < RT; ++rt)
#pragma unroll
    for (int nt = 0; nt < 4; ++nt) acc[rt][nt] = (f32x4){0.f, 0.f, 0.f, 0.f};

  const unsigned short* ap[RT];
#pragma unroll
  for (int rt = 0; rt < RT; ++rt) {
    int row = rowBase + rt * 16 + lr;
    if (row >= M) row = M - 1;
    ap[rt] = Xb + (size_t)row * K + lk * 8;
  }
  const unsigned short* bp = Wt + (size_t)(n0 + lr) * K + lk * 8;

#pragma unroll
  for (int k0 = 0; k0 < K; k0 += 32) {
    bf16x8 a[RT], b[4];
#pragma unroll
    for (int rt = 0; rt < RT; ++rt) a[rt] = *(const bf16x8*)(ap[rt] + k0);
#pragma unroll
    for (int nt = 0; nt < 4; ++nt) b[nt] = *(const bf16x8*)(bp + (size_t)nt * 16 * K + k0);
#pragma unroll
    for (int rt = 0; rt < RT; ++rt)
#pragma unroll
      for (int nt = 0; nt < 4; ++nt)
        acc[rt][nt] = __builtin_amdgcn_mfma_f32_16x16x32_bf16(a[rt], b[nt], acc[rt][nt], 0, 0, 0);
  }

#pragma unroll
  for (int nt = 0; nt < 4; ++nt) {
    float bv = bias[n0 + nt * 16 + lr];
#pragma unroll
    for (int rt = 0; rt < RT; ++rt) {
#pragma unroll
      for (int r = 0; r < 4; ++r) {
        int row = rowBase + rt * 16 + lk * 4 + r;
        if (row < M) Y[(size_t)row * N + n0 + nt * 16 + lr] = f2bf(acc[rt][nt][r] + bv);
      }
    }
  }
}

// ---------------- CSR build ----------------
__global__ void hist_deg(const int* __restrict__ dst, int* __restrict__ deg, int Ee) {
  int e = blockIdx.x * blockDim.x + threadIdx.x;
  if (e < Ee) atomicAdd(&deg[dst[e]], 1);
}

__global__ void scan_deg(const int* __restrict__ deg, int* __restrict__ rowptr, int n) {
  __shared__ int tot[1024];
  const int t = threadIdx.x;
  const int chunk = (n + 1023) / 1024;
  const int lo = t * chunk;
  const int hi = min(n, lo + chunk);
  int s = 0;
  for (int i = lo; i < hi; ++i) s += deg[i];
  tot[t] = s;
  __syncthreads();
  for (int off = 1; off < 1024; off <<= 1) {
    int v = 0;
    if (t >= off) v = tot[t - off];
    __syncthreads();
    if (t >= off) tot[t] += v;
    __syncthreads();
  }
  int run = (t == 0) ? 0 : tot[t - 1];
  for (int i = lo; i < hi; ++i) { rowptr[i] = run; run += deg[i]; }
  if (t == 1023) rowptr[n] = tot[1023];
}

__global__ void fill_csr(const int* __restrict__ src, const int* __restrict__ dst,
                         const int* __restrict__ rowptr, int* __restrict__ cursor,
                         int* __restrict__ csr_src, int Ee) {
  int e = blockIdx.x * blockDim.x + threadIdx.x;
  if (e >= Ee) return;
  int d = dst[e];
  int p = atomicAdd(&cursor[d], 1);
  csr_src[rowptr[d] + p] = src[e];
}

// ---------------- fused GATv2 aggregation + bias + LayerNorm (H=4, bf16 out) ----------------
// 8 edge-groups of 8 lanes; lane holds 8 channels. Per-channel math in f2
// (ext_vector float2, native ops -> backend may select v_pk_* VOP3P).
__global__ __launch_bounds__(256) void gat_fused4(
    const unsigned short* __restrict__ xlb, const unsigned short* __restrict__ xrb,
    const float* __restrict__ att,
    const int* __restrict__ rowptr, const int* __restrict__ csr_src,
    const float* __restrict__ bo, const float* __restrict__ gam,
    const float* __restrict__ bet, unsigned short* __restrict__ outp, int n) {
  const int OUT = 256;
  const int t = threadIdx.x;
  const int wv = t >> 6, lane = t & 63;
  const int grp = lane >> 3, c8 = lane & 7;
  __shared__ float red[4];
  const int node = blockIdx.x;
  const int cb = wv * 64 + c8 * 8;

  f2 xr2[4];
  {
    uint4 p = *(const uint4*)(xrb + (size_t)node * OUT + cb);
    xr2[0] = bfpair(p.x); xr2[1] = bfpair(p.y); xr2[2] = bfpair(p.z); xr2[3] = bfpair(p.w);
  }
  const int r0 = rowptr[node];
  const int r1 = rowptr[node + 1];

  f2 at2[4];
  {
    float4 a0 = *(const float4*)(att + cb);
    float4 a1 = *(const float4*)(att + cb + 4);
    at2[0] = (f2){a0.x * L2E, a0.y * L2E}; at2[1] = (f2){a0.z * L2E, a0.w * L2E};
    at2[2] = (f2){a1.x * L2E, a1.y * L2E}; at2[3] = (f2){a1.z * L2E, a1.w * L2E};
  }

  float s = 0.f;
  f2 o2[4];
#pragma unroll
  for (int j = 0; j < 4; ++j) o2[j] = (f2){0.f, 0.f};

  uint4 vpk = {0u, 0u, 0u, 0u};
  {
    int i0 = r0 + grp;
    if (i0 < r1) vpk = *(const uint4*)(xlb + (size_t)csr_src[i0] * OUT + cb);
  }
  bool valid = (r0 + grp) < r1;

  for (int base = r0; base < r1; base += 8) {
    const uint4 pc = vpk;
    const bool vld = valid;
    int inext = base + 8 + grp;
    valid = inext < r1;
    if (valid) vpk = *(const uint4*)(xlb + (size_t)csr_src[inext] * OUT + cb);

    f2 v0 = bfpair(pc.x), v1 = bfpair(pc.y), v2 = bfpair(pc.z), v3 = bfpair(pc.w);
    f2 e0 = v0 + xr2[0]; e0 = __builtin_elementwise_max(e0, e0 * LRELU_SLOPE);
    f2 e1 = v1 + xr2[1]; e1 = __builtin_elementwise_max(e1, e1 * LRELU_SLOPE);
    f2 e2 = v2 + xr2[2]; e2 = __builtin_elementwise_max(e2, e2 * LRELU_SLOPE);
    f2 e3 = v3 + xr2[3]; e3 = __builtin_elementwise_max(e3, e3 * LRELU_SLOPE);
    f2 sc2 = e0 * at2[0];
    sc2 += e1 * at2[1];
    sc2 += e2 * at2[2];
    sc2 += e3 * at2[3];
    float sc = sc2.x + sc2.y;
    sc += __shfl_xor(sc, 1);
    sc += __shfl_xor(sc, 2);
    sc += __shfl_xor(sc, 4);
    if (!vld) sc = -INFINITY;
    const float w = fast_exp2(sc);   // exp2(-inf)=0 for invalid
    s += w;
    o2[0] += v0 * w;
    o2[1] += v1 * w;
    o2[2] += v2 * w;
    o2[3] += v3 * w;
  }

  float o[8] = {o2[0].x, o2[0].y, o2[1].x, o2[1].y, o2[2].x, o2[2].y, o2[3].x, o2[3].y};
  // combine the 8 edge-groups
#pragma unroll
  for (int off = 8; off < 64; off <<= 1) {
#pragma unroll
    for (int i = 0; i < 8; ++i) o[i] += __shfl_xor(o[i], off);
    s += __shfl_xor(s, off);
  }

  const float inv = 1.f / (s + 1e-16f);
  float val[8];
  {
    float4 b0 = *(const float4*)(bo + cb);
    float4 b1 = *(const float4*)(bo + cb + 4);
    val[0] = fmaf(o[0], inv, b0.x); val[1] = fmaf(o[1], inv, b0.y);
    val[2] = fmaf(o[2], inv, b0.z); val[3] = fmaf(o[3], inv, b0.w);
    val[4] = fmaf(o[4], inv, b1.x); val[5] = fmaf(o[5], inv, b1.y);
    val[6] = fmaf(o[6], inv, b1.z); val[7] = fmaf(o[7], inv, b1.w);
  }

  // ---- LayerNorm over 256 channels ----
  float ls = 0.f;
#pragma unroll
  for (int i = 0; i < 8; ++i) ls += val[i];
  ls += __shfl_xor(ls, 1);
  ls += __shfl_xor(ls, 2);
  ls += __shfl_xor(ls, 4);
  if (lane == 0) red[wv] = ls;
  __syncthreads();
  float mu = (red[0] + red[1] + red[2] + red[3]) * (1.f / 256.f);
  float d[8], q = 0.f;
#pragma unroll
  for (int i = 0; i < 8; ++i) { d[i] = val[i] - mu; q = fmaf(d[i], d[i], q); }
  q += __shfl_xor(q, 1);
  q += __shfl_xor(q, 2);
  q += __shfl_xor(q, 4);
  __syncthreads();
  if (lane == 0) red[wv] = q;
  __syncthreads();
  float var = (red[0] + red[1] + red[2] + red[3]) * (1.f / 256.f);
  const float rs = rsqrtf(var + 1e-5f);

  if (grp == 0) {
    float4 g0 = *(const float4*)(gam + cb);
    float4 g1 = *(const float4*)(gam + cb + 4);
    float4 e0 = *(const float4*)(bet + cb);
    float4 e1 = *(const float4*)(bet + cb + 4);
    float rv[8];
    rv[0] = fmaf(d[0] * rs, g0.x, e0.x); rv[1] = fmaf(d[1] * rs, g0.y, e0.y);
    rv[2] = fmaf(d[2] * rs, g0.z, e0.z); rv[3] = fmaf(d[3] * rs, g0.w, e0.w);
    rv[4] = fmaf(d[4] * rs, g1.x, e1.x); rv[5] = fmaf(d[5] * rs, g1.y, e1.y);
    rv[6] = fmaf(d[6] * rs, g1.z, e1.z); rv[7] = fmaf(d[7] * rs, g1.w, e1.w);
    unsigned short rb[8];
#pragma unroll
    for (int i = 0; i < 8; ++i) rb[i] = f2bf(rv[i]);
    *(bf16x8*)(outp + (size_t)node * OUT + cb) = *(bf16x8*)rb;
  }
}

// ---------------- layer-3 GAT (H=1) + LayerNorm + fused final linear 64->64 ----------------
// 512 threads = 8 waves = 8 nodes per block; linW staged once per block.
__global__ __launch_bounds__(512) void gat1_lin(
    const unsigned short* __restrict__ xlb, const unsigned short* __restrict__ xrb,
    const float* __restrict__ att,
    const int* __restrict__ rowptr, const int* __restrict__ csr_src,
    const float* __restrict__ bo, const float* __restrict__ gam,
    const float* __restrict__ bet,
    const float* __restrict__ linW, const float* __restrict__ linb,
    float* __restrict__ outp, int n) {
  const int OUT = 64;
  const int t = threadIdx.x;
  const int wv = t >> 6, lane = t & 63;
  const int grp = lane >> 3, c8 = lane & 7;
  __shared__ float lw[64][64];
  __shared__ float hbuf[8][64];
  for (int i = t; i < 4096; i += 512) lw[i >> 6][i & 63] = linW[i];

  const int node = blockIdx.x * 8 + wv;
  const bool active = node < n;
  const int cb = c8 * 8;

  f2 xr2[4];
  int r0 = 0, r1 = 0;
  if (active) {
    uint4 p = *(const uint4*)(xrb + (size_t)node * OUT + cb);
    xr2[0] = bfpair(p.x); xr2[1] = bfpair(p.y); xr2[2] = bfpair(p.z); xr2[3] = bfpair(p.w);
    r0 = rowptr[node];
    r1 = rowptr[node + 1];
  } else {
#pragma unroll
    for (int j = 0; j < 4; ++j) xr2[j] = (f2){0.f, 0.f};
  }
  f2 at2[4];
  {
    float4 a0 = *(const float4*)(att + cb);
    float4 a1 = *(const float4*)(att + cb + 4);
    at2[0] = (f2){a0.x * L2E, a0.y * L2E}; at2[1] = (f2){a0.z * L2E, a0.w * L2E};
    at2[2] = (f2){a1.x * L2E, a1.y * L2E}; at2[3] = (f2){a1.z * L2E, a1.w * L2E};
  }

  float s = 0.f;
  f2 o2[4];
#pragma unroll
  for (int j = 0; j < 4; ++j) o2[j] = (f2){0.f, 0.f};

  uint4 vpk = {0u, 0u, 0u, 0u};
  {
    int i0 = r0 + grp;
    if (i0 < r1) vpk = *(const uint4*)(xlb + (size_t)csr_src[i0] * OUT + cb);
  }
  bool valid = (r0 + grp) < r1;

  for (int base = r0; base < r1; base += 8) {
    const uint4 pc = vpk;
    const bool vld = valid;
    int inext = base + 8 + grp;
    valid = inext < r1;
    if (valid) vpk = *(const uint4*)(xlb + (size_t)csr_src[inext] * OUT + cb);

    f2 v0 = bfpair(pc.x), v1 = bfpair(pc.y), v2 = bfpair(pc.z), v3 = bfpair(pc.w);
    f2 e0 = v0 + xr2[0]; e0 = __builtin_elementwise_max(e0, e0 * LRELU_SLOPE);
    f2 e1 = v1 + xr2[1]; e1 = __builtin_elementwise_max(e1, e1 * LRELU_SLOPE);
    f2 e2 = v2 + xr2[2]; e2 = __builtin_elementwise_max(e2, e2 * LRELU_SLOPE);
    f2 e3 = v3 + xr2[3]; e3 = __builtin_elementwise_max(e3, e3 * LRELU_SLOPE);
    f2 sc2 = e0 * at2[0];
    sc2 += e1 * at2[1];
    sc2 += e2 * at2[2];
    sc2 += e3 * at2[3];
    float sc = sc2.x + sc2.y;
    sc += __shfl_xor(sc, 1);
    sc += __shfl_xor(sc, 2);
    sc += __shfl_xor(sc, 4);
    if (!vld) sc = -INFINITY;
    const float w = fast_exp2(sc);
    s += w;
    o2[0] += v0 * w;
    o2[1] += v1 * w;
    o2[2] += v2 * w;
    o2[3] += v3 * w;
  }

  float o[8] = {o2[0].x, o2[0].y, o2[1].x, o2[1].y, o2[2].x, o2[2].y, o2[3].x, o2[3].y};
#pragma unroll
  for (int off = 8; off < 64; off <<= 1) {
#pragma unroll
    for (int i = 0; i < 8; ++i) o[i] += __shfl_xor(o[i], off);
    s += __shfl_xor(s, off);
  }

  const float inv = 1.f / (s + 1e-16f);
  float val[8];
  {
    float4 b0 = *(const float4*)(bo + cb);
    float4 b1 = *(const float4*)(bo + cb + 4);
    val[0] = fmaf(o[0], inv, b0.x); val[1] = fmaf(o[1], inv, b0.y);
    val[2] = fmaf(o[2], inv, b0.z); val[3] = fmaf(o[3], inv, b0.w);
    val[4] = fmaf(o[4], inv, b1.x); val[5] = fmaf(o[5], inv, b1.y);
    val[6] = fmaf(o[6], inv, b1.z); val[7] = fmaf(o[7], inv, b1.w);
  }

  // LN over 64 channels
  float ls = 0.f;
#pragma unroll
  for (int i = 0; i < 8; ++i) ls += val[i];
  ls += __shfl_xor(ls, 1);
  ls += __shfl_xor(ls, 2);
  ls += __shfl_xor(ls, 4);
  float mu = ls * (1.f / 64.f);
  float d[8], q = 0.f;
#pragma unroll
  for (int i = 0; i < 8; ++i) { d[i] = val[i] - mu; q = fmaf(d[i], d[i], q); }
  q += __shfl_xor(q, 1);
  q += __shfl_xor(q, 2);
  q += __shfl_xor(q, 4);
  float var = q * (1.f / 64.f);
  const float rs = rsqrtf(var + 1e-5f);

  if (grp == 0) {
    float4 g0 = *(const float4*)(gam + cb);
    float4 g1 = *(const float4*)(gam + cb + 4);
    float4 e0 = *(const float4*)(bet + cb);
    float4 e1 = *(const float4*)(bet + cb + 4);
    float* hb = &hbuf[wv][cb];
    hb[0] = fmaf(d[0] * rs, g0.x, e0.x); hb[1] = fmaf(d[1] * rs, g0.y, e0.y);
    hb[2] = fmaf(d[2] * rs, g0.z, e0.z); hb[3] = fmaf(d[3] * rs, g0.w, e0.w);
    hb[4] = fmaf(d[4] * rs, g1.x, e1.x); hb[5] = fmaf(d[5] * rs, g1.y, e1.y);
    hb[6] = fmaf(d[6] * rs, g1.z, e1.z); hb[7] = fmaf(d[7] * rs, g1.w, e1.w);
  }
  __syncthreads();

  float acc = linb[lane];
#pragma unroll 8
  for (int k = 0; k < 64; ++k) acc = fmaf(hbuf[wv][k], lw[k][lane], acc);
  if (active) outp[(size_t)node * 64 + lane] = acc;
}

extern "C" void kernel_launch(void* const* d_in, const int* in_sizes, int n_in,
                              void* d_out, int out_size, void* d_ws, size_t ws_size,
                              hipStream_t stream) {
  const float* x    = (const float*)d_in[0];
  const int*   eidx = (const int*)d_in[1];
  const int Nn = in_sizes[0] / 128;
  const int Ee = in_sizes[1] / 2;
  const int* src = eidx;
  const int* dst = eidx + Ee;

  const float* W1l = (const float*)d_in[3];  const float* b1l = (const float*)d_in[4];
  const float* W1r = (const float*)d_in[5];  const float* b1r = (const float*)d_in[6];
  const float* a1  = (const float*)d_in[7];  const float* bo1 = (const float*)d_in[8];
  const float* g1  = (const float*)d_in[9];  const float* be1 = (const float*)d_in[10];
  const float* W2l = (const float*)d_in[11]; const float* b2l = (const float*)d_in[12];
  const float* W2r = (const float*)d_in[13]; const float* b2r = (const float*)d_in[14];
  const float* a2  = (const float*)d_in[15]; const float* bo2 = (const float*)d_in[16];
  const float* g2  = (const float*)d_in[17]; const float* be2 = (const float*)d_in[18];
  const float* W3l = (const float*)d_in[19]; const float* b3l = (const float*)d_in[20];
  const float* W3r = (const float*)d_in[21]; const float* b3r = (const float*)d_in[22];
  const float* a3  = (const float*)d_in[23]; const float* bo3 = (const float*)d_in[24];
  const float* g3  = (const float*)d_in[25]; const float* be3 = (const float*)d_in[26];
  const float* linW = (const float*)d_in[27]; const float* linb = (const float*)d_in[28];

  char* ws = (char*)d_ws;
  unsigned short* xl   = (unsigned short*)ws; ws += (size_t)Nn * 256 * 2;
  unsigned short* xr   = (unsigned short*)ws; ws += (size_t)Nn * 256 * 2;
  unsigned short* Xb   = (unsigned short*)ws; ws += (size_t)Nn * 256 * 2;
  unsigned short* Wt1l = (unsigned short*)ws; ws += 256 * 128 * 2;
  unsigned short* Wt1r = (unsigned short*)ws; ws += 256 * 128 * 2;
  unsigned short* Wt2l = (unsigned short*)ws; ws += 256 * 256 * 2;
  unsigned short* Wt2r = (unsigned short*)ws; ws += 256 * 256 * 2;
  unsigned short* Wt3l = (unsigned short*)ws; ws += 64 * 256 * 2;
  unsigned short* Wt3r = (unsigned short*)ws; ws += 64 * 256 * 2;
  int*   deg    = (int*)ws;    ws += (size_t)Nn * 4;
  int*   cursor = (int*)ws;    ws += (size_t)Nn * 4;
  int*   rowptr = (int*)ws;    ws += (size_t)(Nn + 1) * 4;
  int*   csr_src= (int*)ws;    ws += (size_t)Ee * 4;

  const int eblk = (Ee + 255) / 256;

  // ---------------- CSR build (by dst) + all weight conversions ----------------
  hipMemsetAsync(deg, 0, (size_t)Nn * 4, stream);
  hipMemsetAsync(cursor, 0, (size_t)Nn * 4, stream);
  hist_deg<<<eblk, 256, 0, stream>>>(dst, deg, Ee);
  wt_cvt_all<<<dim3(32, 6), 256, 0, stream>>>(W1l, W1r, W2l, W2r, W3l, W3r,
                                              Wt1l, Wt1r, Wt2l, Wt2r, Wt3l, Wt3r);
  scan_deg<<<1, 1024, 0, stream>>>(deg, rowptr, Nn);
  fill_csr<<<eblk, 256, 0, stream>>>(src, dst, rowptr, cursor, csr_src, Ee);

  // ---------------- layer 1: 128 -> 4x64 ----------------
  cvt_bf16<<<(Nn * 128 / 4 + 255) / 256, 256, 0, stream>>>(x, Xb, Nn * 128 / 4);
  gemm_mfma2<128, 4><<<dim3((Nn + 255) / 256, 8), 256, 0, stream>>>(
      Xb, Wt1l, Wt1r, b1l, b1r, xl, xr, Nn, 256);
  gat_fused4<<<Nn, 256, 0, stream>>>(xl, xr, a1, rowptr, csr_src, bo1, g1, be1, Xb, Nn);

  // ---------------- layer 2: 256 -> 4x64 ----------------
  gemm_mfma2<256, 4><<<dim3((Nn + 255) / 256, 8), 256, 0, stream>>>(
      Xb, Wt2l, Wt2r, b2l, b2r, xl, xr, Nn, 256);
  gat_fused4<<<Nn, 256, 0, stream>>>(xl, xr, a2, rowptr, csr_src, bo2, g2, be2, Xb, Nn);

  // ---------------- layer 3: 256 -> 1x64 + LN + final linear ----------------
  gemm_mfma2<256, 1><<<dim3((Nn + 63) / 64, 2), 256, 0, stream>>>(
      Xb, Wt3l, Wt3r, b3l, b3r, xl, xr, Nn, 64);
  gat1_lin<<<(Nn + 7) / 8, 512, 0, stream>>>(xl, xr, a3, rowptr, csr_src, bo3, g3, be3,
                                             linW, linb, (float*)d_out, Nn);
}

// Round 10
// 555.298 us; speedup vs baseline: 1.2594x; 1.1193x over previous
//
#include <hip/hip_runtime.h>
#include <math.h>

#define LRELU_SLOPE 0.2f
#define L2E 1.4426950408889634f

typedef __attribute__((ext_vector_type(8))) short bf16x8;
typedef __attribute__((ext_vector_type(4))) float f32x4;
typedef __attribute__((ext_vector_type(2))) float f2;

__device__ __forceinline__ float fast_exp2(float x) {
  float r; asm("v_exp_f32 %0, %1" : "=v"(r) : "v"(x)); return r;
}

// ---------------- f32 <-> bf16 helpers ----------------
__device__ __forceinline__ unsigned short f2bf(float f) {
  unsigned u = __float_as_uint(f);
  return (unsigned short)((u + 0x7FFFu + ((u >> 16) & 1u)) >> 16);
}
// packed u32 (two bf16) -> f2
__device__ __forceinline__ f2 bfpair(unsigned p) {
  f2 r;
  r.x = __uint_as_float(p << 16);
  r.y = __uint_as_float(p & 0xffff0000u);
  return r;
}

__global__ void cvt_bf16(const float* __restrict__ in, unsigned short* __restrict__ out, int n4) {
  int i = blockIdx.x * blockDim.x + threadIdx.x;
  if (i >= n4) return;
  float4 v = *(const float4*)(in + (size_t)i * 4);
  ushort4 o;
  o.x = f2bf(v.x); o.y = f2bf(v.y); o.z = f2bf(v.z); o.w = f2bf(v.w);
  *(ushort4*)(out + (size_t)i * 4) = o;
}

// all six weight mats W[K][N] f32 -> Wt[N][K] bf16 in one dispatch
__global__ void wt_cvt_all(
    const float* __restrict__ W1l, const float* __restrict__ W1r,
    const float* __restrict__ W2l, const float* __restrict__ W2r,
    const float* __restrict__ W3l, const float* __restrict__ W3r,
    unsigned short* __restrict__ Wt1l, unsigned short* __restrict__ Wt1r,
    unsigned short* __restrict__ Wt2l, unsigned short* __restrict__ Wt2r,
    unsigned short* __restrict__ Wt3l, unsigned short* __restrict__ Wt3r) {
  const float* W; unsigned short* Wt; int K, N;
  switch (blockIdx.y) {
    case 0: W = W1l; Wt = Wt1l; K = 128; N = 256; break;
    case 1: W = W1r; Wt = Wt1r; K = 128; N = 256; break;
    case 2: W = W2l; Wt = Wt2l; K = 256; N = 256; break;
    case 3: W = W2r; Wt = Wt2r; K = 256; N = 256; break;
    case 4: W = W3l; Wt = Wt3l; K = 256; N = 64;  break;
    default: W = W3r; Wt = Wt3r; K = 256; N = 64; break;
  }
  int i = blockIdx.x * blockDim.x + threadIdx.x;
  int k8s = K / 8;
  int n = i / k8s, k8 = i - n * k8s;
  if (n >= N) return;
  unsigned short tmp[8];
#pragma unroll
  for (int j = 0; j < 8; ++j) tmp[j] = f2bf(W[(size_t)(k8 * 8 + j) * N + n]);
  *(bf16x8*)(Wt + (size_t)n * K + k8 * 8) = *(bf16x8*)tmp;
}

// ---------------- MFMA GEMM pair: Y{0,1}[M][N](bf16) = Xb @ Wt{0,1}^T + bias ----------------
template<int K, int RT>
__global__ __launch_bounds__(256) void gemm_mfma2(
    const unsigned short* __restrict__ Xb,
    const unsigned short* __restrict__ Wt0, const unsigned short* __restrict__ Wt1,
    const float* __restrict__ bias0, const float* __restrict__ bias1,
    unsigned short* __restrict__ Y0, unsigned short* __restrict__ Y1, int M, int N) {
  const int nblk = N >> 6;
  const int side = blockIdx.y / nblk;
  const int n0 = (blockIdx.y - side * nblk) * 64;
  const unsigned short* Wt = side ? Wt1 : Wt0;
  const float* bias = side ? bias1 : bias0;
  unsigned short* Y = side ? Y1 : Y0;

  const int t = threadIdx.x, w = t >> 6, l = t & 63;
  const int lr = l & 15, lk = l >> 4;
  const int rowBase = blockIdx.x * (RT * 64) + w * (RT * 16);

  f32x4 acc[RT][4];
#pragma unroll
  for (int rt = 0; rt < RT; ++rt)
#pragma unroll
    for (int nt = 0; nt < 4; ++nt) acc[rt][nt] = (f32x4){0.f, 0.f, 0.f, 0.f};

  const unsigned short* ap[RT];
#pragma unroll
  for (int rt = 0; rt < RT; ++rt) {
    int row = rowBase + rt * 16 + lr;
    if (row >= M) row = M - 1;
    ap[rt] = Xb + (size_t)row * K + lk * 8;
  }
  const unsigned short* bp = Wt + (size_t)(n0 + lr) * K + lk * 8;

#pragma unroll
  for (int k0 = 0; k0 < K; k0 += 32) {
    bf16x8 a[RT], b[4];
#pragma unroll
    for (int rt = 0; rt < RT; ++rt) a[rt] = *(const bf16x8*)(ap[rt] + k0);
#pragma unroll
    for (int nt = 0; nt < 4; ++nt) b[nt] = *(const bf16x8*)(bp + (size_t)nt * 16 * K + k0);
#pragma unroll
    for (int rt = 0; rt < RT; ++rt)
#pragma unroll
      for (int nt = 0; nt < 4; ++nt)
        acc[rt][nt] = __builtin_amdgcn_mfma_f32_16x16x32_bf16(a[rt], b[nt], acc[rt][nt], 0, 0, 0);
  }

#pragma unroll
  for (int nt = 0; nt < 4; ++nt) {
    float bv = bias[n0 + nt * 16 + lr];
#pragma unroll
    for (int rt = 0; rt < RT; ++rt) {
#pragma unroll
      for (int r = 0; r < 4; ++r) {
        int row = rowBase + rt * 16 + lk * 4 + r;
        if (row < M) Y[(size_t)row * N + n0 + nt * 16 + lr] = f2bf(acc[rt][nt][r] + bv);
      }
    }
  }
}

// ---------------- CSR build ----------------
__global__ void hist_deg(const int* __restrict__ dst, int* __restrict__ deg, int Ee) {
  int e = blockIdx.x * blockDim.x + threadIdx.x;
  if (e < Ee) atomicAdd(&deg[dst[e]], 1);
}

__global__ void scan_deg(const int* __restrict__ deg, int* __restrict__ rowptr, int n) {
  __shared__ int tot[1024];
  const int t = threadIdx.x;
  const int chunk = (n + 1023) / 1024;
  const int lo = t * chunk;
  const int hi = min(n, lo + chunk);
  int s = 0;
  for (int i = lo; i < hi; ++i) s += deg[i];
  tot[t] = s;
  __syncthreads();
  for (int off = 1; off < 1024; off <<= 1) {
    int v = 0;
    if (t >= off) v = tot[t - off];
    __syncthreads();
    if (t >= off) tot[t] += v;
    __syncthreads();
  }
  int run = (t == 0) ? 0 : tot[t - 1];
  for (int i = lo; i < hi; ++i) { rowptr[i] = run; run += deg[i]; }
  if (t == 1023) rowptr[n] = tot[1023];
}

__global__ void fill_csr(const int* __restrict__ src, const int* __restrict__ dst,
                         const int* __restrict__ rowptr, int* __restrict__ cursor,
                         int* __restrict__ csr_src, int Ee) {
  int e = blockIdx.x * blockDim.x + threadIdx.x;
  if (e >= Ee) return;
  int d = dst[e];
  int p = atomicAdd(&cursor[d], 1);
  csr_src[rowptr[d] + p] = src[e];
}

// ---------------- fused GATv2 aggregation + bias + LayerNorm (H=4, bf16 out) ----------------
// ONE WAVE PER NODE: lane = 4 contiguous channels (head = lane>>4).
// Per edge: whole wave covers all 4 heads; score reduce = 4 shfl within
// 16-lane head group. 2 edges/iter for ILP. No LDS, no barriers.
__global__ __launch_bounds__(256) void gat_fused4(
    const unsigned short* __restrict__ xlb, const unsigned short* __restrict__ xrb,
    const float* __restrict__ att,
    const int* __restrict__ rowptr, const int* __restrict__ csr_src,
    const float* __restrict__ bo, const float* __restrict__ gam,
    const float* __restrict__ bet, unsigned short* __restrict__ outp, int n) {
  const int t = threadIdx.x;
  const int wv = t >> 6, lane = t & 63;
  const int node = blockIdx.x * 4 + wv;
  if (node >= n) return;
  const int cb = lane * 4;

  uint2 xp = *(const uint2*)(xrb + (size_t)node * 256 + cb);
  const f2 xr0 = bfpair(xp.x), xr1 = bfpair(xp.y);
  const float4 a4 = *(const float4*)(att + cb);
  const f2 at0 = {a4.x * L2E, a4.y * L2E};
  const f2 at1 = {a4.z * L2E, a4.w * L2E};

  const int r0 = rowptr[node], r1 = rowptr[node + 1];
  float s = 0.f;
  f2 o0 = {0.f, 0.f}, o1 = {0.f, 0.f};

  if (r0 < r1) {
    const int last = r1 - 1;
    uint2 va = *(const uint2*)(xlb + (size_t)csr_src[r0] * 256 + cb);
    uint2 vb = *(const uint2*)(xlb + (size_t)csr_src[min(r0 + 1, last)] * 256 + cb);
    for (int i = r0; i < r1; i += 2) {
      const uint2 ca = va, cbv = vb;
      const bool vldb = (i + 1) < r1;
      if (i + 2 < r1) {
        va = *(const uint2*)(xlb + (size_t)csr_src[i + 2] * 256 + cb);
        vb = *(const uint2*)(xlb + (size_t)csr_src[min(i + 3, last)] * 256 + cb);
      }
      const f2 va0 = bfpair(ca.x), va1 = bfpair(ca.y);
      const f2 vb0 = bfpair(cbv.x), vb1 = bfpair(cbv.y);
      f2 ea0 = va0 + xr0; ea0 = __builtin_elementwise_max(ea0, ea0 * LRELU_SLOPE);
      f2 ea1 = va1 + xr1; ea1 = __builtin_elementwise_max(ea1, ea1 * LRELU_SLOPE);
      f2 eb0 = vb0 + xr0; eb0 = __builtin_elementwise_max(eb0, eb0 * LRELU_SLOPE);
      f2 eb1 = vb1 + xr1; eb1 = __builtin_elementwise_max(eb1, eb1 * LRELU_SLOPE);
      f2 sa2 = ea0 * at0; sa2 += ea1 * at1;
      f2 sb2 = eb0 * at0; sb2 += eb1 * at1;
      float sa = sa2.x + sa2.y;
      float sb = sb2.x + sb2.y;
      sa += __shfl_xor(sa, 1); sb += __shfl_xor(sb, 1);
      sa += __shfl_xor(sa, 2); sb += __shfl_xor(sb, 2);
      sa += __shfl_xor(sa, 4); sb += __shfl_xor(sb, 4);
      sa += __shfl_xor(sa, 8); sb += __shfl_xor(sb, 8);
      if (!vldb) sb = -INFINITY;
      const float wa = fast_exp2(sa);
      const float wb = fast_exp2(sb);
      s += wa + wb;
      o0 += va0 * wa; o1 += va1 * wa;
      o0 += vb0 * wb; o1 += vb1 * wb;
    }
  }

  const float inv = 1.f / (s + 1e-16f);
  const float4 b4 = *(const float4*)(bo + cb);
  const float v0 = fmaf(o0.x, inv, b4.x);
  const float v1 = fmaf(o0.y, inv, b4.y);
  const float v2 = fmaf(o1.x, inv, b4.z);
  const float v3 = fmaf(o1.y, inv, b4.w);

  // LayerNorm over 256 channels = full-wave reduce (no LDS, no barriers)
  float ls = v0 + v1 + v2 + v3;
#pragma unroll
  for (int off = 1; off < 64; off <<= 1) ls += __shfl_xor(ls, off);
  const float mu = ls * (1.f / 256.f);
  const float d0 = v0 - mu, d1 = v1 - mu, d2 = v2 - mu, d3 = v3 - mu;
  float q = d0 * d0 + d1 * d1 + d2 * d2 + d3 * d3;
#pragma unroll
  for (int off = 1; off < 64; off <<= 1) q += __shfl_xor(q, off);
  const float rs = rsqrtf(q * (1.f / 256.f) + 1e-5f);

  const float4 g4 = *(const float4*)(gam + cb);
  const float4 e4 = *(const float4*)(bet + cb);
  ushort4 res;
  res.x = f2bf(fmaf(d0 * rs, g4.x, e4.x));
  res.y = f2bf(fmaf(d1 * rs, g4.y, e4.y));
  res.z = f2bf(fmaf(d2 * rs, g4.z, e4.z));
  res.w = f2bf(fmaf(d3 * rs, g4.w, e4.w));
  *(ushort4*)(outp + (size_t)node * 256 + cb) = res;
}

// ---------------- layer-3 GAT (H=1) + LayerNorm + fused final linear 64->64 ----------------
// 512 threads = 8 waves = 8 nodes per block; linW staged once per block.
__global__ __launch_bounds__(512) void gat1_lin(
    const unsigned short* __restrict__ xlb, const unsigned short* __restrict__ xrb,
    const float* __restrict__ att,
    const int* __restrict__ rowptr, const int* __restrict__ csr_src,
    const float* __restrict__ bo, const float* __restrict__ gam,
    const float* __restrict__ bet,
    const float* __restrict__ linW, const float* __restrict__ linb,
    float* __restrict__ outp, int n) {
  const int OUT = 64;
  const int t = threadIdx.x;
  const int wv = t >> 6, lane = t & 63;
  const int grp = lane >> 3, c8 = lane & 7;
  __shared__ float lw[64][64];
  __shared__ float hbuf[8][64];
  for (int i = t; i < 4096; i += 512) lw[i >> 6][i & 63] = linW[i];

  const int node = blockIdx.x * 8 + wv;
  const bool active = node < n;
  const int cb = c8 * 8;

  f2 xr2[4];
  int r0 = 0, r1 = 0;
  if (active) {
    uint4 p = *(const uint4*)(xrb + (size_t)node * OUT + cb);
    xr2[0] = bfpair(p.x); xr2[1] = bfpair(p.y); xr2[2] = bfpair(p.z); xr2[3] = bfpair(p.w);
    r0 = rowptr[node];
    r1 = rowptr[node + 1];
  } else {
#pragma unroll
    for (int j = 0; j < 4; ++j) xr2[j] = (f2){0.f, 0.f};
  }
  f2 at2[4];
  {
    float4 a0 = *(const float4*)(att + cb);
    float4 a1 = *(const float4*)(att + cb + 4);
    at2[0] = (f2){a0.x * L2E, a0.y * L2E}; at2[1] = (f2){a0.z * L2E, a0.w * L2E};
    at2[2] = (f2){a1.x * L2E, a1.y * L2E}; at2[3] = (f2){a1.z * L2E, a1.w * L2E};
  }

  float s = 0.f;
  f2 o2[4];
#pragma unroll
  for (int j = 0; j < 4; ++j) o2[j] = (f2){0.f, 0.f};

  uint4 vpk = {0u, 0u, 0u, 0u};
  {
    int i0 = r0 + grp;
    if (i0 < r1) vpk = *(const uint4*)(xlb + (size_t)csr_src[i0] * OUT + cb);
  }
  bool valid = (r0 + grp) < r1;

  for (int base = r0; base < r1; base += 8) {
    const uint4 pc = vpk;
    const bool vld = valid;
    int inext = base + 8 + grp;
    valid = inext < r1;
    if (valid) vpk = *(const uint4*)(xlb + (size_t)csr_src[inext] * OUT + cb);

    f2 v0 = bfpair(pc.x), v1 = bfpair(pc.y), v2 = bfpair(pc.z), v3 = bfpair(pc.w);
    f2 e0 = v0 + xr2[0]; e0 = __builtin_elementwise_max(e0, e0 * LRELU_SLOPE);
    f2 e1 = v1 + xr2[1]; e1 = __builtin_elementwise_max(e1, e1 * LRELU_SLOPE);
    f2 e2 = v2 + xr2[2]; e2 = __builtin_elementwise_max(e2, e2 * LRELU_SLOPE);
    f2 e3 = v3 + xr2[3]; e3 = __builtin_elementwise_max(e3, e3 * LRELU_SLOPE);
    f2 sc2 = e0 * at2[0];
    sc2 += e1 * at2[1];
    sc2 += e2 * at2[2];
    sc2 += e3 * at2[3];
    float sc = sc2.x + sc2.y;
    sc += __shfl_xor(sc, 1);
    sc += __shfl_xor(sc, 2);
    sc += __shfl_xor(sc, 4);
    if (!vld) sc = -INFINITY;
    const float w = fast_exp2(sc);
    s += w;
    o2[0] += v0 * w;
    o2[1] += v1 * w;
    o2[2] += v2 * w;
    o2[3] += v3 * w;
  }

  float o[8] = {o2[0].x, o2[0].y, o2[1].x, o2[1].y, o2[2].x, o2[2].y, o2[3].x, o2[3].y};
#pragma unroll
  for (int off = 8; off < 64; off <<= 1) {
#pragma unroll
    for (int i = 0; i < 8; ++i) o[i] += __shfl_xor(o[i], off);
    s += __shfl_xor(s, off);
  }

  const float inv = 1.f / (s + 1e-16f);
  float val[8];
  {
    float4 b0 = *(const float4*)(bo + cb);
    float4 b1 = *(const float4*)(bo + cb + 4);
    val[0] = fmaf(o[0], inv, b0.x); val[1] = fmaf(o[1], inv, b0.y);
    val[2] = fmaf(o[2], inv, b0.z); val[3] = fmaf(o[3], inv, b0.w);
    val[4] = fmaf(o[4], inv, b1.x); val[5] = fmaf(o[5], inv, b1.y);
    val[6] = fmaf(o[6], inv, b1.z); val[7] = fmaf(o[7], inv, b1.w);
  }

  // LN over 64 channels
  float ls = 0.f;
#pragma unroll
  for (int i = 0; i < 8; ++i) ls += val[i];
  ls += __shfl_xor(ls, 1);
  ls += __shfl_xor(ls, 2);
  ls += __shfl_xor(ls, 4);
  float mu = ls * (1.f / 64.f);
  float d[8], q = 0.f;
#pragma unroll
  for (int i = 0; i < 8; ++i) { d[i] = val[i] - mu; q = fmaf(d[i], d[i], q); }
  q += __shfl_xor(q, 1);
  q += __shfl_xor(q, 2);
  q += __shfl_xor(q, 4);
  float var = q * (1.f / 64.f);
  const float rs = rsqrtf(var + 1e-5f);

  if (grp == 0) {
    float4 g0 = *(const float4*)(gam + cb);
    float4 g1 = *(const float4*)(gam + cb + 4);
    float4 e0 = *(const float4*)(bet + cb);
    float4 e1 = *(const float4*)(bet + cb + 4);
    float* hb = &hbuf[wv][cb];
    hb[0] = fmaf(d[0] * rs, g0.x, e0.x); hb[1] = fmaf(d[1] * rs, g0.y, e0.y);
    hb[2] = fmaf(d[2] * rs, g0.z, e0.z); hb[3] = fmaf(d[3] * rs, g0.w, e0.w);
    hb[4] = fmaf(d[4] * rs, g1.x, e1.x); hb[5] = fmaf(d[5] * rs, g1.y, e1.y);
    hb[6] = fmaf(d[6] * rs, g1.z, e1.z); hb[7] = fmaf(d[7] * rs, g1.w, e1.w);
  }
  __syncthreads();

  float acc = linb[lane];
#pragma unroll 8
  for (int k = 0; k < 64; ++k) acc = fmaf(hbuf[wv][k], lw[k][lane], acc);
  if (active) outp[(size_t)node * 64 + lane] = acc;
}

extern "C" void kernel_launch(void* const* d_in, const int* in_sizes, int n_in,
                              void* d_out, int out_size, void* d_ws, size_t ws_size,
                              hipStream_t stream) {
  const float* x    = (const float*)d_in[0];
  const int*   eidx = (const int*)d_in[1];
  const int Nn = in_sizes[0] / 128;
  const int Ee = in_sizes[1] / 2;
  const int* src = eidx;
  const int* dst = eidx + Ee;

  const float* W1l = (const float*)d_in[3];  const float* b1l = (const float*)d_in[4];
  const float* W1r = (const float*)d_in[5];  const float* b1r = (const float*)d_in[6];
  const float* a1  = (const float*)d_in[7];  const float* bo1 = (const float*)d_in[8];
  const float* g1  = (const float*)d_in[9];  const float* be1 = (const float*)d_in[10];
  const float* W2l = (const float*)d_in[11]; const float* b2l = (const float*)d_in[12];
  const float* W2r = (const float*)d_in[13]; const float* b2r = (const float*)d_in[14];
  const float* a2  = (const float*)d_in[15]; const float* bo2 = (const float*)d_in[16];
  const float* g2  = (const float*)d_in[17]; const float* be2 = (const float*)d_in[18];
  const float* W3l = (const float*)d_in[19]; const float* b3l = (const float*)d_in[20];
  const float* W3r = (const float*)d_in[21]; const float* b3r = (const float*)d_in[22];
  const float* a3  = (const float*)d_in[23]; const float* bo3 = (const float*)d_in[24];
  const float* g3  = (const float*)d_in[25]; const float* be3 = (const float*)d_in[26];
  const float* linW = (const float*)d_in[27]; const float* linb = (const float*)d_in[28];

  char* ws = (char*)d_ws;
  unsigned short* xl   = (unsigned short*)ws; ws += (size_t)Nn * 256 * 2;
  unsigned short* xr   = (unsigned short*)ws; ws += (size_t)Nn * 256 * 2;
  unsigned short* Xb   = (unsigned short*)ws; ws += (size_t)Nn * 256 * 2;
  unsigned short* Wt1l = (unsigned short*)ws; ws += 256 * 128 * 2;
  unsigned short* Wt1r = (unsigned short*)ws; ws += 256 * 128 * 2;
  unsigned short* Wt2l = (unsigned short*)ws; ws += 256 * 256 * 2;
  unsigned short* Wt2r = (unsigned short*)ws; ws += 256 * 256 * 2;
  unsigned short* Wt3l = (unsigned short*)ws; ws += 64 * 256 * 2;
  unsigned short* Wt3r = (unsigned short*)ws; ws += 64 * 256 * 2;
  int*   deg    = (int*)ws;    ws += (size_t)Nn * 4;
  int*   cursor = (int*)ws;    ws += (size_t)Nn * 4;
  int*   rowptr = (int*)ws;    ws += (size_t)(Nn + 1) * 4;
  int*   csr_src= (int*)ws;    ws += (size_t)Ee * 4;

  const int eblk = (Ee + 255) / 256;

  // ---------------- CSR build (by dst) + all weight conversions ----------------
  hipMemsetAsync(deg, 0, (size_t)Nn * 4, stream);
  hipMemsetAsync(cursor, 0, (size_t)Nn * 4, stream);
  hist_deg<<<eblk, 256, 0, stream>>>(dst, deg, Ee);
  wt_cvt_all<<<dim3(32, 6), 256, 0, stream>>>(W1l, W1r, W2l, W2r, W3l, W3r,
                                              Wt1l, Wt1r, Wt2l, Wt2r, Wt3l, Wt3r);
  scan_deg<<<1, 1024, 0, stream>>>(deg, rowptr, Nn);
  fill_csr<<<eblk, 256, 0, stream>>>(src, dst, rowptr, cursor, csr_src, Ee);

  // ---------------- layer 1: 128 -> 4x64 ----------------
  cvt_bf16<<<(Nn * 128 / 4 + 255) / 256, 256, 0, stream>>>(x, Xb, Nn * 128 / 4);
  gemm_mfma2<128, 4><<<dim3((Nn + 255) / 256, 8), 256, 0, stream>>>(
      Xb, Wt1l, Wt1r, b1l, b1r, xl, xr, Nn, 256);
  gat_fused4<<<(Nn + 3) / 4, 256, 0, stream>>>(xl, xr, a1, rowptr, csr_src, bo1, g1, be1, Xb, Nn);

  // ---------------- layer 2: 256 -> 4x64 ----------------
  gemm_mfma2<256, 4><<<dim3((Nn + 255) / 256, 8), 256, 0, stream>>>(
      Xb, Wt2l, Wt2r, b2l, b2r, xl, xr, Nn, 256);
  gat_fused4<<<(Nn + 3) / 4, 256, 0, stream>>>(xl, xr, a2, rowptr, csr_src, bo2, g2, be2, Xb, Nn);

  // ---------------- layer 3: 256 -> 1x64 + LN + final linear ----------------
  gemm_mfma2<256, 1><<<dim3((Nn + 63) / 64, 2), 256, 0, stream>>>(
      Xb, Wt3l, Wt3r, b3l, b3r, xl, xr, Nn, 64);
  gat1_lin<<<(Nn + 7) / 8, 512, 0, stream>>>(xl, xr, a3, rowptr, csr_src, bo3, g3, be3,
                                             linW, linb, (float*)d_out, Nn);
}

// Round 11
// 462.738 us; speedup vs baseline: 1.5114x; 1.2000x over previous
//
#include <hip/hip_runtime.h>
#include <math.h>

#define LRELU_SLOPE 0.2f
#define L2E 1.4426950408889634f

typedef __attribute__((ext_vector_type(8))) short bf16x8;
typedef __attribute__((ext_vector_type(4))) float f32x4;
typedef __attribute__((ext_vector_type(2))) float f2;

__device__ __forceinline__ float fast_exp2(float x) {
  float r; asm("v_exp_f32 %0, %1" : "=v"(r) : "v"(x)); return r;
}

// ---------------- f32 <-> bf16 helpers ----------------
__device__ __forceinline__ unsigned short f2bf(float f) {
  unsigned u = __float_as_uint(f);
  return (unsigned short)((u + 0x7FFFu + ((u >> 16) & 1u)) >> 16);
}
// packed u32 (two bf16) -> f2
__device__ __forceinline__ f2 bfpair(unsigned p) {
  f2 r;
  r.x = __uint_as_float(p << 16);
  r.y = __uint_as_float(p & 0xffff0000u);
  return r;
}

__global__ void cvt_bf16(const float* __restrict__ in, unsigned short* __restrict__ out, int n4) {
  int i = blockIdx.x * blockDim.x + threadIdx.x;
  if (i >= n4) return;
  float4 v = *(const float4*)(in + (size_t)i * 4);
  ushort4 o;
  o.x = f2bf(v.x); o.y = f2bf(v.y); o.z = f2bf(v.z); o.w = f2bf(v.w);
  *(ushort4*)(out + (size_t)i * 4) = o;
}

// all six weight mats W[K][N] f32 -> Wt[N][K] bf16 in one dispatch
__global__ void wt_cvt_all(
    const float* __restrict__ W1l, const float* __restrict__ W1r,
    const float* __restrict__ W2l, const float* __restrict__ W2r,
    const float* __restrict__ W3l, const float* __restrict__ W3r,
    unsigned short* __restrict__ Wt1l, unsigned short* __restrict__ Wt1r,
    unsigned short* __restrict__ Wt2l, unsigned short* __restrict__ Wt2r,
    unsigned short* __restrict__ Wt3l, unsigned short* __restrict__ Wt3r) {
  const float* W; unsigned short* Wt; int K, N;
  switch (blockIdx.y) {
    case 0: W = W1l; Wt = Wt1l; K = 128; N = 256; break;
    case 1: W = W1r; Wt = Wt1r; K = 128; N = 256; break;
    case 2: W = W2l; Wt = Wt2l; K = 256; N = 256; break;
    case 3: W = W2r; Wt = Wt2r; K = 256; N = 256; break;
    case 4: W = W3l; Wt = Wt3l; K = 256; N = 64;  break;
    default: W = W3r; Wt = Wt3r; K = 256; N = 64; break;
  }
  int i = blockIdx.x * blockDim.x + threadIdx.x;
  int k8s = K / 8;
  int n = i / k8s, k8 = i - n * k8s;
  if (n >= N) return;
  unsigned short tmp[8];
#pragma unroll
  for (int j = 0; j < 8; ++j) tmp[j] = f2bf(W[(size_t)(k8 * 8 + j) * N + n]);
  *(bf16x8*)(Wt + (size_t)n * K + k8 * 8) = *(bf16x8*)tmp;
}

// ---------------- MFMA GEMM pair: Y{0,1}[M][N](bf16) = Xb @ Wt{0,1}^T + bias ----------------
template<int K, int RT>
__global__ __launch_bounds__(256) void gemm_mfma2(
    const unsigned short* __restrict__ Xb,
    const unsigned short* __restrict__ Wt0, const unsigned short* __restrict__ Wt1,
    const float* __restrict__ bias0, const float* __restrict__ bias1,
    unsigned short* __restrict__ Y0, unsigned short* __restrict__ Y1, int M, int N) {
  const int nblk = N >> 6;
  const int side = blockIdx.y / nblk;
  const int n0 = (blockIdx.y - side * nblk) * 64;
  const unsigned short* Wt = side ? Wt1 : Wt0;
  const float* bias = side ? bias1 : bias0;
  unsigned short* Y = side ? Y1 : Y0;

  const int t = threadIdx.x, w = t >> 6, l = t & 63;
  const int lr = l & 15, lk = l >> 4;
  const int rowBase = blockIdx.x * (RT * 64) + w * (RT * 16);

  f32x4 acc[RT][4];
#pragma unroll
  for (int rt = 0; rt < RT; ++rt)
#pragma unroll
    for (int nt = 0; nt < 4; ++nt) acc[rt][nt] = (f32x4){0.f, 0.f, 0.f, 0.f};

  const unsigned short* ap[RT];
#pragma unroll
  for (int rt = 0; rt < RT; ++rt) {
    int row = rowBase + rt * 16 + lr;
    if (row >= M) row = M - 1;
    ap[rt] = Xb + (size_t)row * K + lk * 8;
  }
  const unsigned short* bp = Wt + (size_t)(n0 + lr) * K + lk * 8;

#pragma unroll
  for (int k0 = 0; k0 < K; k0 += 32) {
    bf16x8 a[RT], b[4];
#pragma unroll
    for (int rt = 0; rt < RT; ++rt) a[rt] = *(const bf16x8*)(ap[rt] + k0);
#pragma unroll
    for (int nt = 0; nt < 4; ++nt) b[nt] = *(const bf16x8*)(bp + (size_t)nt * 16 * K + k0);
#pragma unroll
    for (int rt = 0; rt < RT; ++rt)
#pragma unroll
      for (int nt = 0; nt < 4; ++nt)
        acc[rt][nt] = __builtin_amdgcn_mfma_f32_16x16x32_bf16(a[rt], b[nt], acc[rt][nt], 0, 0, 0);
  }

#pragma unroll
  for (int nt = 0; nt < 4; ++nt) {
    float bv = bias[n0 + nt * 16 + lr];
#pragma unroll
    for (int rt = 0; rt < RT; ++rt) {
#pragma unroll
      for (int r = 0; r < 4; ++r) {
        int row = rowBase + rt * 16 + lk * 4 + r;
        if (row < M) Y[(size_t)row * N + n0 + nt * 16 + lr] = f2bf(acc[rt][nt][r] + bv);
      }
    }
  }
}

// ---------------- CSR build ----------------
__global__ void hist_deg(const int* __restrict__ dst, int* __restrict__ deg, int Ee) {
  int e = blockIdx.x * blockDim.x + threadIdx.x;
  if (e < Ee) atomicAdd(&deg[dst[e]], 1);
}

// parallel scan: per-256-block local exclusive scan -> rowptr; block totals -> bsum
__global__ void scan_blk(const int* __restrict__ deg, int* __restrict__ rowptr,
                         int* __restrict__ bsum, int n) {
  __shared__ int sm[256];
  const int b = blockIdx.x, t = threadIdx.x;
  const int i = b * 256 + t;
  const int v = (i < n) ? deg[i] : 0;
  sm[t] = v;
  __syncthreads();
#pragma unroll
  for (int off = 1; off < 256; off <<= 1) {
    int x = (t >= off) ? sm[t - off] : 0;
    __syncthreads();
    sm[t] += x;
    __syncthreads();
  }
  if (i < n) rowptr[i] = sm[t] - v;   // local exclusive
  if (t == 255) bsum[b] = sm[255];
}

// single-block scan of block sums -> boff; writes rowptr[n]=total
__global__ void scan_top(const int* __restrict__ bsum, int* __restrict__ boff,
                         int* __restrict__ rowptr, int nb, int n) {
  __shared__ int sm[1024];
  const int t = threadIdx.x;
  const int v = (t < nb) ? bsum[t] : 0;
  sm[t] = v;
  __syncthreads();
#pragma unroll
  for (int off = 1; off < 1024; off <<= 1) {
    int x = (t >= off) ? sm[t - off] : 0;
    __syncthreads();
    sm[t] += x;
    __syncthreads();
  }
  if (t < nb) boff[t] = sm[t] - v;    // exclusive
  if (t == 1023) rowptr[n] = sm[1023];
}

__global__ void scan_add(int* __restrict__ rowptr, const int* __restrict__ boff, int n) {
  int i = blockIdx.x * 256 + threadIdx.x;
  if (i < n) rowptr[i] += boff[blockIdx.x];
}

// fill via countdown on deg (no cursor array)
__global__ void fill_csr(const int* __restrict__ src, const int* __restrict__ dst,
                         const int* __restrict__ rowptr, int* __restrict__ deg,
                         int* __restrict__ csr_src, int Ee) {
  int e = blockIdx.x * blockDim.x + threadIdx.x;
  if (e >= Ee) return;
  int d = dst[e];
  int p = atomicSub(&deg[d], 1) - 1;
  csr_src[rowptr[d] + p] = src[e];
}

// ---------------- fused GATv2 aggregation + bias + LayerNorm (H=4, bf16 out) ----------------
// ONE WAVE PER NODE: lane = 4 contiguous channels (head = lane>>4).
// 4 edges per iteration (8 loads in flight, 4 independent shuffle chains).
__global__ __launch_bounds__(256) void gat_fused4(
    const unsigned short* __restrict__ xlb, const unsigned short* __restrict__ xrb,
    const float* __restrict__ att,
    const int* __restrict__ rowptr, const int* __restrict__ csr_src,
    const float* __restrict__ bo, const float* __restrict__ gam,
    const float* __restrict__ bet, unsigned short* __restrict__ outp, int n) {
  const int t = threadIdx.x;
  const int wv = t >> 6, lane = t & 63;
  const int node = blockIdx.x * 4 + wv;
  if (node >= n) return;
  const int cb = lane * 4;

  uint2 xp = *(const uint2*)(xrb + (size_t)node * 256 + cb);
  const f2 xr0 = bfpair(xp.x), xr1 = bfpair(xp.y);
  const float4 a4 = *(const float4*)(att + cb);
  const f2 at0 = {a4.x * L2E, a4.y * L2E};
  const f2 at1 = {a4.z * L2E, a4.w * L2E};

  const int r0 = rowptr[node], r1 = rowptr[node + 1];
  float s = 0.f;
  f2 o0 = {0.f, 0.f}, o1 = {0.f, 0.f};

  if (r0 < r1) {
    const int last = r1 - 1;
    uint2 p0 = *(const uint2*)(xlb + (size_t)csr_src[r0] * 256 + cb);
    uint2 p1 = *(const uint2*)(xlb + (size_t)csr_src[min(r0 + 1, last)] * 256 + cb);
    uint2 p2 = *(const uint2*)(xlb + (size_t)csr_src[min(r0 + 2, last)] * 256 + cb);
    uint2 p3 = *(const uint2*)(xlb + (size_t)csr_src[min(r0 + 3, last)] * 256 + cb);
    for (int i = r0; i < r1; i += 4) {
      const uint2 c0 = p0, c1 = p1, c2 = p2, c3 = p3;
      if (i + 4 < r1) {
        p0 = *(const uint2*)(xlb + (size_t)csr_src[min(i + 4, last)] * 256 + cb);
        p1 = *(const uint2*)(xlb + (size_t)csr_src[min(i + 5, last)] * 256 + cb);
        p2 = *(const uint2*)(xlb + (size_t)csr_src[min(i + 6, last)] * 256 + cb);
        p3 = *(const uint2*)(xlb + (size_t)csr_src[min(i + 7, last)] * 256 + cb);
      }
      const f2 v00 = bfpair(c0.x), v01 = bfpair(c0.y);
      const f2 v10 = bfpair(c1.x), v11 = bfpair(c1.y);
      const f2 v20 = bfpair(c2.x), v21 = bfpair(c2.y);
      const f2 v30 = bfpair(c3.x), v31 = bfpair(c3.y);

      f2 e;
      f2 q0, q1, q2, q3;
      e = v00 + xr0; e = __builtin_elementwise_max(e, e * LRELU_SLOPE); q0 = e * at0;
      e = v01 + xr1; e = __builtin_elementwise_max(e, e * LRELU_SLOPE); q0 += e * at1;
      e = v10 + xr0; e = __builtin_elementwise_max(e, e * LRELU_SLOPE); q1 = e * at0;
      e = v11 + xr1; e = __builtin_elementwise_max(e, e * LRELU_SLOPE); q1 += e * at1;
      e = v20 + xr0; e = __builtin_elementwise_max(e, e * LRELU_SLOPE); q2 = e * at0;
      e = v21 + xr1; e = __builtin_elementwise_max(e, e * LRELU_SLOPE); q2 += e * at1;
      e = v30 + xr0; e = __builtin_elementwise_max(e, e * LRELU_SLOPE); q3 = e * at0;
      e = v31 + xr1; e = __builtin_elementwise_max(e, e * LRELU_SLOPE); q3 += e * at1;

      float s0 = q0.x + q0.y, s1 = q1.x + q1.y, s2 = q2.x + q2.y, s3 = q3.x + q3.y;
      s0 += __shfl_xor(s0, 1); s1 += __shfl_xor(s1, 1);
      s2 += __shfl_xor(s2, 1); s3 += __shfl_xor(s3, 1);
      s0 += __shfl_xor(s0, 2); s1 += __shfl_xor(s1, 2);
      s2 += __shfl_xor(s2, 2); s3 += __shfl_xor(s3, 2);
      s0 += __shfl_xor(s0, 4); s1 += __shfl_xor(s1, 4);
      s2 += __shfl_xor(s2, 4); s3 += __shfl_xor(s3, 4);
      s0 += __shfl_xor(s0, 8); s1 += __shfl_xor(s1, 8);
      s2 += __shfl_xor(s2, 8); s3 += __shfl_xor(s3, 8);
      if (i + 1 >= r1) s1 = -INFINITY;
      if (i + 2 >= r1) s2 = -INFINITY;
      if (i + 3 >= r1) s3 = -INFINITY;
      const float w0 = fast_exp2(s0), w1 = fast_exp2(s1);
      const float w2 = fast_exp2(s2), w3 = fast_exp2(s3);
      s += (w0 + w1) + (w2 + w3);
      o0 += v00 * w0; o1 += v01 * w0;
      o0 += v10 * w1; o1 += v11 * w1;
      o0 += v20 * w2; o1 += v21 * w2;
      o0 += v30 * w3; o1 += v31 * w3;
    }
  }

  const float inv = 1.f / (s + 1e-16f);
  const float4 b4 = *(const float4*)(bo + cb);
  const float v0 = fmaf(o0.x, inv, b4.x);
  const float v1 = fmaf(o0.y, inv, b4.y);
  const float v2 = fmaf(o1.x, inv, b4.z);
  const float v3 = fmaf(o1.y, inv, b4.w);

  // LayerNorm over 256 channels = full-wave reduce (no LDS, no barriers)
  float ls = v0 + v1 + v2 + v3;
#pragma unroll
  for (int off = 1; off < 64; off <<= 1) ls += __shfl_xor(ls, off);
  const float mu = ls * (1.f / 256.f);
  const float d0 = v0 - mu, d1 = v1 - mu, d2 = v2 - mu, d3 = v3 - mu;
  float q = d0 * d0 + d1 * d1 + d2 * d2 + d3 * d3;
#pragma unroll
  for (int off = 1; off < 64; off <<= 1) q += __shfl_xor(q, off);
  const float rs = rsqrtf(q * (1.f / 256.f) + 1e-5f);

  const float4 g4 = *(const float4*)(gam + cb);
  const float4 e4 = *(const float4*)(bet + cb);
  ushort4 res;
  res.x = f2bf(fmaf(d0 * rs, g4.x, e4.x));
  res.y = f2bf(fmaf(d1 * rs, g4.y, e4.y));
  res.z = f2bf(fmaf(d2 * rs, g4.z, e4.z));
  res.w = f2bf(fmaf(d3 * rs, g4.w, e4.w));
  *(ushort4*)(outp + (size_t)node * 256 + cb) = res;
}

// ---------------- layer-3 GAT (H=1) + LayerNorm + fused final linear 64->64 ----------------
// 512 threads = 8 waves = 8 nodes per block; linW staged once per block.
__global__ __launch_bounds__(512) void gat1_lin(
    const unsigned short* __restrict__ xlb, const unsigned short* __restrict__ xrb,
    const float* __restrict__ att,
    const int* __restrict__ rowptr, const int* __restrict__ csr_src,
    const float* __restrict__ bo, const float* __restrict__ gam,
    const float* __restrict__ bet,
    const float* __restrict__ linW, const float* __restrict__ linb,
    float* __restrict__ outp, int n) {
  const int OUT = 64;
  const int t = threadIdx.x;
  const int wv = t >> 6, lane = t & 63;
  const int grp = lane >> 3, c8 = lane & 7;
  __shared__ float lw[64][64];
  __shared__ float hbuf[8][64];
  for (int i = t; i < 4096; i += 512) lw[i >> 6][i & 63] = linW[i];

  const int node = blockIdx.x * 8 + wv;
  const bool active = node < n;
  const int cb = c8 * 8;

  f2 xr2[4];
  int r0 = 0, r1 = 0;
  if (active) {
    uint4 p = *(const uint4*)(xrb + (size_t)node * OUT + cb);
    xr2[0] = bfpair(p.x); xr2[1] = bfpair(p.y); xr2[2] = bfpair(p.z); xr2[3] = bfpair(p.w);
    r0 = rowptr[node];
    r1 = rowptr[node + 1];
  } else {
#pragma unroll
    for (int j = 0; j < 4; ++j) xr2[j] = (f2){0.f, 0.f};
  }
  f2 at2[4];
  {
    float4 a0 = *(const float4*)(att + cb);
    float4 a1 = *(const float4*)(att + cb + 4);
    at2[0] = (f2){a0.x * L2E, a0.y * L2E}; at2[1] = (f2){a0.z * L2E, a0.w * L2E};
    at2[2] = (f2){a1.x * L2E, a1.y * L2E}; at2[3] = (f2){a1.z * L2E, a1.w * L2E};
  }

  float s = 0.f;
  f2 o2[4];
#pragma unroll
  for (int j = 0; j < 4; ++j) o2[j] = (f2){0.f, 0.f};

  uint4 vpk = {0u, 0u, 0u, 0u};
  {
    int i0 = r0 + grp;
    if (i0 < r1) vpk = *(const uint4*)(xlb + (size_t)csr_src[i0] * OUT + cb);
  }
  bool valid = (r0 + grp) < r1;

  for (int base = r0; base < r1; base += 8) {
    const uint4 pc = vpk;
    const bool vld = valid;
    int inext = base + 8 + grp;
    valid = inext < r1;
    if (valid) vpk = *(const uint4*)(xlb + (size_t)csr_src[inext] * OUT + cb);

    f2 v0 = bfpair(pc.x), v1 = bfpair(pc.y), v2 = bfpair(pc.z), v3 = bfpair(pc.w);
    f2 e0 = v0 + xr2[0]; e0 = __builtin_elementwise_max(e0, e0 * LRELU_SLOPE);
    f2 e1 = v1 + xr2[1]; e1 = __builtin_elementwise_max(e1, e1 * LRELU_SLOPE);
    f2 e2 = v2 + xr2[2]; e2 = __builtin_elementwise_max(e2, e2 * LRELU_SLOPE);
    f2 e3 = v3 + xr2[3]; e3 = __builtin_elementwise_max(e3, e3 * LRELU_SLOPE);
    f2 sc2 = e0 * at2[0];
    sc2 += e1 * at2[1];
    sc2 += e2 * at2[2];
    sc2 += e3 * at2[3];
    float sc = sc2.x + sc2.y;
    sc += __shfl_xor(sc, 1);
    sc += __shfl_xor(sc, 2);
    sc += __shfl_xor(sc, 4);
    if (!vld) sc = -INFINITY;
    const float w = fast_exp2(sc);
    s += w;
    o2[0] += v0 * w;
    o2[1] += v1 * w;
    o2[2] += v2 * w;
    o2[3] += v3 * w;
  }

  float o[8] = {o2[0].x, o2[0].y, o2[1].x, o2[1].y, o2[2].x, o2[2].y, o2[3].x, o2[3].y};
#pragma unroll
  for (int off = 8; off < 64; off <<= 1) {
#pragma unroll
    for (int i = 0; i < 8; ++i) o[i] += __shfl_xor(o[i], off);
    s += __shfl_xor(s, off);
  }

  const float inv = 1.f / (s + 1e-16f);
  float val[8];
  {
    float4 b0 = *(const float4*)(bo + cb);
    float4 b1 = *(const float4*)(bo + cb + 4);
    val[0] = fmaf(o[0], inv, b0.x); val[1] = fmaf(o[1], inv, b0.y);
    val[2] = fmaf(o[2], inv, b0.z); val[3] = fmaf(o[3], inv, b0.w);
    val[4] = fmaf(o[4], inv, b1.x); val[5] = fmaf(o[5], inv, b1.y);
    val[6] = fmaf(o[6], inv, b1.z); val[7] = fmaf(o[7], inv, b1.w);
  }

  // LN over 64 channels
  float ls = 0.f;
#pragma unroll
  for (int i = 0; i < 8; ++i) ls += val[i];
  ls += __shfl_xor(ls, 1);
  ls += __shfl_xor(ls, 2);
  ls += __shfl_xor(ls, 4);
  float mu = ls * (1.f / 64.f);
  float d[8], q = 0.f;
#pragma unroll
  for (int i = 0; i < 8; ++i) { d[i] = val[i] - mu; q = fmaf(d[i], d[i], q); }
  q += __shfl_xor(q, 1);
  q += __shfl_xor(q, 2);
  q += __shfl_xor(q, 4);
  float var = q * (1.f / 64.f);
  const float rs = rsqrtf(var + 1e-5f);

  if (grp == 0) {
    float4 g0 = *(const float4*)(gam + cb);
    float4 g1 = *(const float4*)(gam + cb + 4);
    float4 e0 = *(const float4*)(bet + cb);
    float4 e1 = *(const float4*)(bet + cb + 4);
    float* hb = &hbuf[wv][cb];
    hb[0] = fmaf(d[0] * rs, g0.x, e0.x); hb[1] = fmaf(d[1] * rs, g0.y, e0.y);
    hb[2] = fmaf(d[2] * rs, g0.z, e0.z); hb[3] = fmaf(d[3] * rs, g0.w, e0.w);
    hb[4] = fmaf(d[4] * rs, g1.x, e1.x); hb[5] = fmaf(d[5] * rs, g1.y, e1.y);
    hb[6] = fmaf(d[6] * rs, g1.z, e1.z); hb[7] = fmaf(d[7] * rs, g1.w, e1.w);
  }
  __syncthreads();

  float acc = linb[lane];
#pragma unroll 8
  for (int k = 0; k < 64; ++k) acc = fmaf(hbuf[wv][k], lw[k][lane], acc);
  if (active) outp[(size_t)node * 64 + lane] = acc;
}

extern "C" void kernel_launch(void* const* d_in, const int* in_sizes, int n_in,
                              void* d_out, int out_size, void* d_ws, size_t ws_size,
                              hipStream_t stream) {
  const float* x    = (const float*)d_in[0];
  const int*   eidx = (const int*)d_in[1];
  const int Nn = in_sizes[0] / 128;
  const int Ee = in_sizes[1] / 2;
  const int* src = eidx;
  const int* dst = eidx + Ee;

  const float* W1l = (const float*)d_in[3];  const float* b1l = (const float*)d_in[4];
  const float* W1r = (const float*)d_in[5];  const float* b1r = (const float*)d_in[6];
  const float* a1  = (const float*)d_in[7];  const float* bo1 = (const float*)d_in[8];
  const float* g1  = (const float*)d_in[9];  const float* be1 = (const float*)d_in[10];
  const float* W2l = (const float*)d_in[11]; const float* b2l = (const float*)d_in[12];
  const float* W2r = (const float*)d_in[13]; const float* b2r = (const float*)d_in[14];
  const float* a2  = (const float*)d_in[15]; const float* bo2 = (const float*)d_in[16];
  const float* g2  = (const float*)d_in[17]; const float* be2 = (const float*)d_in[18];
  const float* W3l = (const float*)d_in[19]; const float* b3l = (const float*)d_in[20];
  const float* W3r = (const float*)d_in[21]; const float* b3r = (const float*)d_in[22];
  const float* a3  = (const float*)d_in[23]; const float* bo3 = (const float*)d_in[24];
  const float* g3  = (const float*)d_in[25]; const float* be3 = (const float*)d_in[26];
  const float* linW = (const float*)d_in[27]; const float* linb = (const float*)d_in[28];

  char* ws = (char*)d_ws;
  unsigned short* xl   = (unsigned short*)ws; ws += (size_t)Nn * 256 * 2;
  unsigned short* xr   = (unsigned short*)ws; ws += (size_t)Nn * 256 * 2;
  unsigned short* Xb   = (unsigned short*)ws; ws += (size_t)Nn * 256 * 2;
  unsigned short* Wt1l = (unsigned short*)ws; ws += 256 * 128 * 2;
  unsigned short* Wt1r = (unsigned short*)ws; ws += 256 * 128 * 2;
  unsigned short* Wt2l = (unsigned short*)ws; ws += 256 * 256 * 2;
  unsigned short* Wt2r = (unsigned short*)ws; ws += 256 * 256 * 2;
  unsigned short* Wt3l = (unsigned short*)ws; ws += 64 * 256 * 2;
  unsigned short* Wt3r = (unsigned short*)ws; ws += 64 * 256 * 2;
  int*   deg    = (int*)ws;    ws += (size_t)Nn * 4;
  int*   rowptr = (int*)ws;    ws += (size_t)(Nn + 1) * 4;
  int*   bsum   = (int*)ws;    ws += 1024 * 4;
  int*   boff   = (int*)ws;    ws += 1024 * 4;
  int*   csr_src= (int*)ws;    ws += (size_t)Ee * 4;

  const int eblk = (Ee + 255) / 256;
  const int nblk = (Nn + 255) / 256;   // 196 for N=50000 (<=1024 supported)

  // ---------------- CSR build (by dst) + all weight conversions ----------------
  hipMemsetAsync(deg, 0, (size_t)Nn * 4, stream);
  hist_deg<<<eblk, 256, 0, stream>>>(dst, deg, Ee);
  wt_cvt_all<<<dim3(32, 6), 256, 0, stream>>>(W1l, W1r, W2l, W2r, W3l, W3r,
                                              Wt1l, Wt1r, Wt2l, Wt2r, Wt3l, Wt3r);
  scan_blk<<<nblk, 256, 0, stream>>>(deg, rowptr, bsum, Nn);
  scan_top<<<1, 1024, 0, stream>>>(bsum, boff, rowptr, nblk, Nn);
  scan_add<<<nblk, 256, 0, stream>>>(rowptr, boff, Nn);
  fill_csr<<<eblk, 256, 0, stream>>>(src, dst, rowptr, deg, csr_src, Ee);

  // ---------------- layer 1: 128 -> 4x64 ----------------
  cvt_bf16<<<(Nn * 128 / 4 + 255) / 256, 256, 0, stream>>>(x, Xb, Nn * 128 / 4);
  gemm_mfma2<128, 4><<<dim3((Nn + 255) / 256, 8), 256, 0, stream>>>(
      Xb, Wt1l, Wt1r, b1l, b1r, xl, xr, Nn, 256);
  gat_fused4<<<(Nn + 3) / 4, 256, 0, stream>>>(xl, xr, a1, rowptr, csr_src, bo1, g1, be1, Xb, Nn);

  // ---------------- layer 2: 256 -> 4x64 ----------------
  gemm_mfma2<256, 4><<<dim3((Nn + 255) / 256, 8), 256, 0, stream>>>(
      Xb, Wt2l, Wt2r, b2l, b2r, xl, xr, Nn, 256);
  gat_fused4<<<(Nn + 3) / 4, 256, 0, stream>>>(xl, xr, a2, rowptr, csr_src, bo2, g2, be2, Xb, Nn);

  // ---------------- layer 3: 256 -> 1x64 + LN + final linear ----------------
  gemm_mfma2<256, 1><<<dim3((Nn + 63) / 64, 2), 256, 0, stream>>>(
      Xb, Wt3l, Wt3r, b3l, b3r, xl, xr, Nn, 64);
  gat1_lin<<<(Nn + 7) / 8, 512, 0, stream>>>(xl, xr, a3, rowptr, csr_src, bo3, g3, be3,
                                             linW, linb, (float*)d_out, Nn);
}

// Round 12
// 453.543 us; speedup vs baseline: 1.5420x; 1.0203x over previous
//
#include <hip/hip_runtime.h>
#include <math.h>

#define LRELU_SLOPE 0.2f
#define L2E 1.4426950408889634f

typedef __attribute__((ext_vector_type(8))) short bf16x8;
typedef __attribute__((ext_vector_type(4))) float f32x4;
typedef __attribute__((ext_vector_type(2))) float f2;

__device__ __forceinline__ float fast_exp2(float x) {
  float r; asm("v_exp_f32 %0, %1" : "=v"(r) : "v"(x)); return r;
}

// ---------------- f32 <-> bf16 helpers ----------------
__device__ __forceinline__ unsigned short f2bf(float f) {
  unsigned u = __float_as_uint(f);
  return (unsigned short)((u + 0x7FFFu + ((u >> 16) & 1u)) >> 16);
}
// packed u32 (two bf16) -> f2
__device__ __forceinline__ f2 bfpair(unsigned p) {
  f2 r;
  r.x = __uint_as_float(p << 16);
  r.y = __uint_as_float(p & 0xffff0000u);
  return r;
}

__global__ void cvt_bf16(const float* __restrict__ in, unsigned short* __restrict__ out, int n4) {
  int i = blockIdx.x * blockDim.x + threadIdx.x;
  if (i >= n4) return;
  float4 v = *(const float4*)(in + (size_t)i * 4);
  ushort4 o;
  o.x = f2bf(v.x); o.y = f2bf(v.y); o.z = f2bf(v.z); o.w = f2bf(v.w);
  *(ushort4*)(out + (size_t)i * 4) = o;
}

// all six weight mats W[K][N] f32 -> Wt[N][K] bf16 in one dispatch
__global__ void wt_cvt_all(
    const float* __restrict__ W1l, const float* __restrict__ W1r,
    const float* __restrict__ W2l, const float* __restrict__ W2r,
    const float* __restrict__ W3l, const float* __restrict__ W3r,
    unsigned short* __restrict__ Wt1l, unsigned short* __restrict__ Wt1r,
    unsigned short* __restrict__ Wt2l, unsigned short* __restrict__ Wt2r,
    unsigned short* __restrict__ Wt3l, unsigned short* __restrict__ Wt3r) {
  const float* W; unsigned short* Wt; int K, N;
  switch (blockIdx.y) {
    case 0: W = W1l; Wt = Wt1l; K = 128; N = 256; break;
    case 1: W = W1r; Wt = Wt1r; K = 128; N = 256; break;
    case 2: W = W2l; Wt = Wt2l; K = 256; N = 256; break;
    case 3: W = W2r; Wt = Wt2r; K = 256; N = 256; break;
    case 4: W = W3l; Wt = Wt3l; K = 256; N = 64;  break;
    default: W = W3r; Wt = Wt3r; K = 256; N = 64; break;
  }
  int i = blockIdx.x * blockDim.x + threadIdx.x;
  int k8s = K / 8;
  int n = i / k8s, k8 = i - n * k8s;
  if (n >= N) return;
  unsigned short tmp[8];
#pragma unroll
  for (int j = 0; j < 8; ++j) tmp[j] = f2bf(W[(size_t)(k8 * 8 + j) * N + n]);
  *(bf16x8*)(Wt + (size_t)n * K + k8 * 8) = *(bf16x8*)tmp;
}

// ---------------- dual-side MFMA GEMM with LDS A-staging ----------------
// 512 thr = 8 waves. Block: 64 rows x 256 cols x both sides.
// A-tile (64 x K) staged once in LDS (padded, conflict-free); B streams from L2.
// Wave w: side = w>>2, col strip = (w&3)*64. Y is bf16, N=256.
template<int K>
__global__ __launch_bounds__(512) void gemm_dual(
    const unsigned short* __restrict__ Xb,
    const unsigned short* __restrict__ Wt0, const unsigned short* __restrict__ Wt1,
    const float* __restrict__ bias0, const float* __restrict__ bias1,
    unsigned short* __restrict__ Y0, unsigned short* __restrict__ Y1, int M) {
  constexpr int LDK = K + 8;                 // pad 16B: bank-tiling conflict-free
  __shared__ unsigned short As[64 * LDK];
  const int t = threadIdx.x, w = t >> 6, l = t & 63;
  const int lr = l & 15, lk = l >> 4;
  const int rowBase = blockIdx.x * 64;

  // stage A: 64 rows x K u16, 16B per (thread, iter)
  constexpr int SPR = K / 8;                 // 16B segments per row
  constexpr int ITER = (64 * SPR) / 512;
#pragma unroll
  for (int i = 0; i < ITER; ++i) {
    int idx = i * 512 + t;
    int row = idx / SPR, seg = idx - row * SPR;
    int gr = rowBase + row; if (gr >= M) gr = M - 1;
    *(uint4*)(As + row * LDK + seg * 8) = *(const uint4*)(Xb + (size_t)gr * K + seg * 8);
  }
  __syncthreads();

  const int side = w >> 2;
  const int n0 = (w & 3) * 64;
  const unsigned short* Wt = side ? Wt1 : Wt0;
  const float* bias = side ? bias1 : bias0;
  unsigned short* Y = side ? Y1 : Y0;

  f32x4 acc[4][4];
#pragma unroll
  for (int rt = 0; rt < 4; ++rt)
#pragma unroll
    for (int nt = 0; nt < 4; ++nt) acc[rt][nt] = (f32x4){0.f, 0.f, 0.f, 0.f};

  const unsigned short* bp = Wt + (size_t)(n0 + lr) * K + lk * 8;
  const unsigned short* ap = As + lr * LDK + lk * 8;

#pragma unroll
  for (int k0 = 0; k0 < K; k0 += 32) {
    bf16x8 a[4], b[4];
#pragma unroll
    for (int rt = 0; rt < 4; ++rt) a[rt] = *(const bf16x8*)(ap + rt * 16 * LDK + k0);
#pragma unroll
    for (int nt = 0; nt < 4; ++nt) b[nt] = *(const bf16x8*)(bp + nt * 16 * K + k0);
#pragma unroll
    for (int rt = 0; rt < 4; ++rt)
#pragma unroll
      for (int nt = 0; nt < 4; ++nt)
        acc[rt][nt] = __builtin_amdgcn_mfma_f32_16x16x32_bf16(a[rt], b[nt], acc[rt][nt], 0, 0, 0);
  }

#pragma unroll
  for (int nt = 0; nt < 4; ++nt) {
    float bv = bias[n0 + nt * 16 + lr];
#pragma unroll
    for (int rt = 0; rt < 4; ++rt) {
#pragma unroll
      for (int r = 0; r < 4; ++r) {
        int row = rowBase + rt * 16 + lk * 4 + r;
        if (row < M) Y[(size_t)row * 256 + n0 + nt * 16 + lr] = f2bf(acc[rt][nt][r] + bv);
      }
    }
  }
}

// ---------------- MFMA GEMM pair (layer 3, N=64) ----------------
template<int K, int RT>
__global__ __launch_bounds__(256) void gemm_mfma2(
    const unsigned short* __restrict__ Xb,
    const unsigned short* __restrict__ Wt0, const unsigned short* __restrict__ Wt1,
    const float* __restrict__ bias0, const float* __restrict__ bias1,
    unsigned short* __restrict__ Y0, unsigned short* __restrict__ Y1, int M, int N) {
  const int nblk = N >> 6;
  const int side = blockIdx.y / nblk;
  const int n0 = (blockIdx.y - side * nblk) * 64;
  const unsigned short* Wt = side ? Wt1 : Wt0;
  const float* bias = side ? bias1 : bias0;
  unsigned short* Y = side ? Y1 : Y0;

  const int t = threadIdx.x, w = t >> 6, l = t & 63;
  const int lr = l & 15, lk = l >> 4;
  const int rowBase = blockIdx.x * (RT * 64) + w * (RT * 16);

  f32x4 acc[RT][4];
#pragma unroll
  for (int rt = 0; rt < RT; ++rt)
#pragma unroll
    for (int nt = 0; nt < 4; ++nt) acc[rt][nt] = (f32x4){0.f, 0.f, 0.f, 0.f};

  const unsigned short* ap[RT];
#pragma unroll
  for (int rt = 0; rt < RT; ++rt) {
    int row = rowBase + rt * 16 + lr;
    if (row >= M) row = M - 1;
    ap[rt] = Xb + (size_t)row * K + lk * 8;
  }
  const unsigned short* bp = Wt + (size_t)(n0 + lr) * K + lk * 8;

#pragma unroll
  for (int k0 = 0; k0 < K; k0 += 32) {
    bf16x8 a[RT], b[4];
#pragma unroll
    for (int rt = 0; rt < RT; ++rt) a[rt] = *(const bf16x8*)(ap[rt] + k0);
#pragma unroll
    for (int nt = 0; nt < 4; ++nt) b[nt] = *(const bf16x8*)(bp + (size_t)nt * 16 * K + k0);
#pragma unroll
    for (int rt = 0; rt < RT; ++rt)
#pragma unroll
      for (int nt = 0; nt < 4; ++nt)
        acc[rt][nt] = __builtin_amdgcn_mfma_f32_16x16x32_bf16(a[rt], b[nt], acc[rt][nt], 0, 0, 0);
  }

#pragma unroll
  for (int nt = 0; nt < 4; ++nt) {
    float bv = bias[n0 + nt * 16 + lr];
#pragma unroll
    for (int rt = 0; rt < RT; ++rt) {
#pragma unroll
      for (int r = 0; r < 4; ++r) {
        int row = rowBase + rt * 16 + lk * 4 + r;
        if (row < M) Y[(size_t)row * N + n0 + nt * 16 + lr] = f2bf(acc[rt][nt][r] + bv);
      }
    }
  }
}

// ---------------- CSR build ----------------
__global__ void hist_deg(const int* __restrict__ dst, int* __restrict__ deg, int Ee) {
  int e = blockIdx.x * blockDim.x + threadIdx.x;
  if (e < Ee) atomicAdd(&deg[dst[e]], 1);
}

__global__ void scan_blk(const int* __restrict__ deg, int* __restrict__ rowptr,
                         int* __restrict__ bsum, int n) {
  __shared__ int sm[256];
  const int b = blockIdx.x, t = threadIdx.x;
  const int i = b * 256 + t;
  const int v = (i < n) ? deg[i] : 0;
  sm[t] = v;
  __syncthreads();
#pragma unroll
  for (int off = 1; off < 256; off <<= 1) {
    int x = (t >= off) ? sm[t - off] : 0;
    __syncthreads();
    sm[t] += x;
    __syncthreads();
  }
  if (i < n) rowptr[i] = sm[t] - v;
  if (t == 255) bsum[b] = sm[255];
}

__global__ void scan_top(const int* __restrict__ bsum, int* __restrict__ boff,
                         int* __restrict__ rowptr, int nb, int n) {
  __shared__ int sm[1024];
  const int t = threadIdx.x;
  const int v = (t < nb) ? bsum[t] : 0;
  sm[t] = v;
  __syncthreads();
#pragma unroll
  for (int off = 1; off < 1024; off <<= 1) {
    int x = (t >= off) ? sm[t - off] : 0;
    __syncthreads();
    sm[t] += x;
    __syncthreads();
  }
  if (t < nb) boff[t] = sm[t] - v;
  if (t == 1023) rowptr[n] = sm[1023];
}

__global__ void scan_add(int* __restrict__ rowptr, const int* __restrict__ boff, int n) {
  int i = blockIdx.x * 256 + threadIdx.x;
  if (i < n) rowptr[i] += boff[blockIdx.x];
}

__global__ void fill_csr(const int* __restrict__ src, const int* __restrict__ dst,
                         const int* __restrict__ rowptr, int* __restrict__ deg,
                         int* __restrict__ csr_src, int Ee) {
  int e = blockIdx.x * blockDim.x + threadIdx.x;
  if (e >= Ee) return;
  int d = dst[e];
  int p = atomicSub(&deg[d], 1) - 1;
  csr_src[rowptr[d] + p] = src[e];
}

// ---------------- fused GATv2 aggregation + bias + LayerNorm (H=4, bf16 out) ----------------
// ONE WAVE PER NODE: lane = 4 contiguous channels. 4 edges/iter.
__global__ __launch_bounds__(256) void gat_fused4(
    const unsigned short* __restrict__ xlb, const unsigned short* __restrict__ xrb,
    const float* __restrict__ att,
    const int* __restrict__ rowptr, const int* __restrict__ csr_src,
    const float* __restrict__ bo, const float* __restrict__ gam,
    const float* __restrict__ bet, unsigned short* __restrict__ outp, int n) {
  const int t = threadIdx.x;
  const int wv = t >> 6, lane = t & 63;
  const int node = blockIdx.x * 4 + wv;
  if (node >= n) return;
  const int cb = lane * 4;

  uint2 xp = *(const uint2*)(xrb + (size_t)node * 256 + cb);
  const f2 xr0 = bfpair(xp.x), xr1 = bfpair(xp.y);
  const float4 a4 = *(const float4*)(att + cb);
  const f2 at0 = {a4.x * L2E, a4.y * L2E};
  const f2 at1 = {a4.z * L2E, a4.w * L2E};

  const int r0 = rowptr[node], r1 = rowptr[node + 1];
  float s = 0.f;
  f2 o0 = {0.f, 0.f}, o1 = {0.f, 0.f};

  if (r0 < r1) {
    const int last = r1 - 1;
    uint2 p0 = *(const uint2*)(xlb + (size_t)csr_src[r0] * 256 + cb);
    uint2 p1 = *(const uint2*)(xlb + (size_t)csr_src[min(r0 + 1, last)] * 256 + cb);
    uint2 p2 = *(const uint2*)(xlb + (size_t)csr_src[min(r0 + 2, last)] * 256 + cb);
    uint2 p3 = *(const uint2*)(xlb + (size_t)csr_src[min(r0 + 3, last)] * 256 + cb);
    for (int i = r0; i < r1; i += 4) {
      const uint2 c0 = p0, c1 = p1, c2 = p2, c3 = p3;
      if (i + 4 < r1) {
        p0 = *(const uint2*)(xlb + (size_t)csr_src[min(i + 4, last)] * 256 + cb);
        p1 = *(const uint2*)(xlb + (size_t)csr_src[min(i + 5, last)] * 256 + cb);
        p2 = *(const uint2*)(xlb + (size_t)csr_src[min(i + 6, last)] * 256 + cb);
        p3 = *(const uint2*)(xlb + (size_t)csr_src[min(i + 7, last)] * 256 + cb);
      }
      const f2 v00 = bfpair(c0.x), v01 = bfpair(c0.y);
      const f2 v10 = bfpair(c1.x), v11 = bfpair(c1.y);
      const f2 v20 = bfpair(c2.x), v21 = bfpair(c2.y);
      const f2 v30 = bfpair(c3.x), v31 = bfpair(c3.y);

      f2 e;
      f2 q0, q1, q2, q3;
      e = v00 + xr0; e = __builtin_elementwise_max(e, e * LRELU_SLOPE); q0 = e * at0;
      e = v01 + xr1; e = __builtin_elementwise_max(e, e * LRELU_SLOPE); q0 += e * at1;
      e = v10 + xr0; e = __builtin_elementwise_max(e, e * LRELU_SLOPE); q1 = e * at0;
      e = v11 + xr1; e = __builtin_elementwise_max(e, e * LRELU_SLOPE); q1 += e * at1;
      e = v20 + xr0; e = __builtin_elementwise_max(e, e * LRELU_SLOPE); q2 = e * at0;
      e = v21 + xr1; e = __builtin_elementwise_max(e, e * LRELU_SLOPE); q2 += e * at1;
      e = v30 + xr0; e = __builtin_elementwise_max(e, e * LRELU_SLOPE); q3 = e * at0;
      e = v31 + xr1; e = __builtin_elementwise_max(e, e * LRELU_SLOPE); q3 += e * at1;

      float s0 = q0.x + q0.y, s1 = q1.x + q1.y, s2 = q2.x + q2.y, s3 = q3.x + q3.y;
      s0 += __shfl_xor(s0, 1); s1 += __shfl_xor(s1, 1);
      s2 += __shfl_xor(s2, 1); s3 += __shfl_xor(s3, 1);
      s0 += __shfl_xor(s0, 2); s1 += __shfl_xor(s1, 2);
      s2 += __shfl_xor(s2, 2); s3 += __shfl_xor(s3, 2);
      s0 += __shfl_xor(s0, 4); s1 += __shfl_xor(s1, 4);
      s2 += __shfl_xor(s2, 4); s3 += __shfl_xor(s3, 4);
      s0 += __shfl_xor(s0, 8); s1 += __shfl_xor(s1, 8);
      s2 += __shfl_xor(s2, 8); s3 += __shfl_xor(s3, 8);
      if (i + 1 >= r1) s1 = -INFINITY;
      if (i + 2 >= r1) s2 = -INFINITY;
      if (i + 3 >= r1) s3 = -INFINITY;
      const float w0 = fast_exp2(s0), w1 = fast_exp2(s1);
      const float w2 = fast_exp2(s2), w3 = fast_exp2(s3);
      s += (w0 + w1) + (w2 + w3);
      o0 += v00 * w0; o1 += v01 * w0;
      o0 += v10 * w1; o1 += v11 * w1;
      o0 += v20 * w2; o1 += v21 * w2;
      o0 += v30 * w3; o1 += v31 * w3;
    }
  }

  const float inv = 1.f / (s + 1e-16f);
  const float4 b4 = *(const float4*)(bo + cb);
  const float v0 = fmaf(o0.x, inv, b4.x);
  const float v1 = fmaf(o0.y, inv, b4.y);
  const float v2 = fmaf(o1.x, inv, b4.z);
  const float v3 = fmaf(o1.y, inv, b4.w);

  float ls = v0 + v1 + v2 + v3;
#pragma unroll
  for (int off = 1; off < 64; off <<= 1) ls += __shfl_xor(ls, off);
  const float mu = ls * (1.f / 256.f);
  const float d0 = v0 - mu, d1 = v1 - mu, d2 = v2 - mu, d3 = v3 - mu;
  float q = d0 * d0 + d1 * d1 + d2 * d2 + d3 * d3;
#pragma unroll
  for (int off = 1; off < 64; off <<= 1) q += __shfl_xor(q, off);
  const float rs = rsqrtf(q * (1.f / 256.f) + 1e-5f);

  const float4 g4 = *(const float4*)(gam + cb);
  const float4 e4 = *(const float4*)(bet + cb);
  ushort4 res;
  res.x = f2bf(fmaf(d0 * rs, g4.x, e4.x));
  res.y = f2bf(fmaf(d1 * rs, g4.y, e4.y));
  res.z = f2bf(fmaf(d2 * rs, g4.z, e4.z));
  res.w = f2bf(fmaf(d3 * rs, g4.w, e4.w));
  *(ushort4*)(outp + (size_t)node * 256 + cb) = res;
}

// ---------------- layer-3 GAT (H=1) + LayerNorm + fused final linear 64->64 ----------------
__global__ __launch_bounds__(512) void gat1_lin(
    const unsigned short* __restrict__ xlb, const unsigned short* __restrict__ xrb,
    const float* __restrict__ att,
    const int* __restrict__ rowptr, const int* __restrict__ csr_src,
    const float* __restrict__ bo, const float* __restrict__ gam,
    const float* __restrict__ bet,
    const float* __restrict__ linW, const float* __restrict__ linb,
    float* __restrict__ outp, int n) {
  const int OUT = 64;
  const int t = threadIdx.x;
  const int wv = t >> 6, lane = t & 63;
  const int grp = lane >> 3, c8 = lane & 7;
  __shared__ float lw[64][64];
  __shared__ float hbuf[8][64];
  for (int i = t; i < 4096; i += 512) lw[i >> 6][i & 63] = linW[i];

  const int node = blockIdx.x * 8 + wv;
  const bool active = node < n;
  const int cb = c8 * 8;

  f2 xr2[4];
  int r0 = 0, r1 = 0;
  if (active) {
    uint4 p = *(const uint4*)(xrb + (size_t)node * OUT + cb);
    xr2[0] = bfpair(p.x); xr2[1] = bfpair(p.y); xr2[2] = bfpair(p.z); xr2[3] = bfpair(p.w);
    r0 = rowptr[node];
    r1 = rowptr[node + 1];
  } else {
#pragma unroll
    for (int j = 0; j < 4; ++j) xr2[j] = (f2){0.f, 0.f};
  }
  f2 at2[4];
  {
    float4 a0 = *(const float4*)(att + cb);
    float4 a1 = *(const float4*)(att + cb + 4);
    at2[0] = (f2){a0.x * L2E, a0.y * L2E}; at2[1] = (f2){a0.z * L2E, a0.w * L2E};
    at2[2] = (f2){a1.x * L2E, a1.y * L2E}; at2[3] = (f2){a1.z * L2E, a1.w * L2E};
  }

  float s = 0.f;
  f2 o2[4];
#pragma unroll
  for (int j = 0; j < 4; ++j) o2[j] = (f2){0.f, 0.f};

  uint4 vpk = {0u, 0u, 0u, 0u};
  {
    int i0 = r0 + grp;
    if (i0 < r1) vpk = *(const uint4*)(xlb + (size_t)csr_src[i0] * OUT + cb);
  }
  bool valid = (r0 + grp) < r1;

  for (int base = r0; base < r1; base += 8) {
    const uint4 pc = vpk;
    const bool vld = valid;
    int inext = base + 8 + grp;
    valid = inext < r1;
    if (valid) vpk = *(const uint4*)(xlb + (size_t)csr_src[inext] * OUT + cb);

    f2 v0 = bfpair(pc.x), v1 = bfpair(pc.y), v2 = bfpair(pc.z), v3 = bfpair(pc.w);
    f2 e0 = v0 + xr2[0]; e0 = __builtin_elementwise_max(e0, e0 * LRELU_SLOPE);
    f2 e1 = v1 + xr2[1]; e1 = __builtin_elementwise_max(e1, e1 * LRELU_SLOPE);
    f2 e2 = v2 + xr2[2]; e2 = __builtin_elementwise_max(e2, e2 * LRELU_SLOPE);
    f2 e3 = v3 + xr2[3]; e3 = __builtin_elementwise_max(e3, e3 * LRELU_SLOPE);
    f2 sc2 = e0 * at2[0];
    sc2 += e1 * at2[1];
    sc2 += e2 * at2[2];
    sc2 += e3 * at2[3];
    float sc = sc2.x + sc2.y;
    sc += __shfl_xor(sc, 1);
    sc += __shfl_xor(sc, 2);
    sc += __shfl_xor(sc, 4);
    if (!vld) sc = -INFINITY;
    const float w = fast_exp2(sc);
    s += w;
    o2[0] += v0 * w;
    o2[1] += v1 * w;
    o2[2] += v2 * w;
    o2[3] += v3 * w;
  }

  float o[8] = {o2[0].x, o2[0].y, o2[1].x, o2[1].y, o2[2].x, o2[2].y, o2[3].x, o2[3].y};
#pragma unroll
  for (int off = 8; off < 64; off <<= 1) {
#pragma unroll
    for (int i = 0; i < 8; ++i) o[i] += __shfl_xor(o[i], off);
    s += __shfl_xor(s, off);
  }

  const float inv = 1.f / (s + 1e-16f);
  float val[8];
  {
    float4 b0 = *(const float4*)(bo + cb);
    float4 b1 = *(const float4*)(bo + cb + 4);
    val[0] = fmaf(o[0], inv, b0.x); val[1] = fmaf(o[1], inv, b0.y);
    val[2] = fmaf(o[2], inv, b0.z); val[3] = fmaf(o[3], inv, b0.w);
    val[4] = fmaf(o[4], inv, b1.x); val[5] = fmaf(o[5], inv, b1.y);
    val[6] = fmaf(o[6], inv, b1.z); val[7] = fmaf(o[7], inv, b1.w);
  }

  float ls = 0.f;
#pragma unroll
  for (int i = 0; i < 8; ++i) ls += val[i];
  ls += __shfl_xor(ls, 1);
  ls += __shfl_xor(ls, 2);
  ls += __shfl_xor(ls, 4);
  float mu = ls * (1.f / 64.f);
  float d[8], q = 0.f;
#pragma unroll
  for (int i = 0; i < 8; ++i) { d[i] = val[i] - mu; q = fmaf(d[i], d[i], q); }
  q += __shfl_xor(q, 1);
  q += __shfl_xor(q, 2);
  q += __shfl_xor(q, 4);
  float var = q * (1.f / 64.f);
  const float rs = rsqrtf(var + 1e-5f);

  if (grp == 0) {
    float4 g0 = *(const float4*)(gam + cb);
    float4 g1 = *(const float4*)(gam + cb + 4);
    float4 e0 = *(const float4*)(bet + cb);
    float4 e1 = *(const float4*)(bet + cb + 4);
    float* hb = &hbuf[wv][cb];
    hb[0] = fmaf(d[0] * rs, g0.x, e0.x); hb[1] = fmaf(d[1] * rs, g0.y, e0.y);
    hb[2] = fmaf(d[2] * rs, g0.z, e0.z); hb[3] = fmaf(d[3] * rs, g0.w, e0.w);
    hb[4] = fmaf(d[4] * rs, g1.x, e1.x); hb[5] = fmaf(d[5] * rs, g1.y, e1.y);
    hb[6] = fmaf(d[6] * rs, g1.z, e1.z); hb[7] = fmaf(d[7] * rs, g1.w, e1.w);
  }
  __syncthreads();

  float acc = linb[lane];
#pragma unroll 8
  for (int k = 0; k < 64; ++k) acc = fmaf(hbuf[wv][k], lw[k][lane], acc);
  if (active) outp[(size_t)node * 64 + lane] = acc;
}

extern "C" void kernel_launch(void* const* d_in, const int* in_sizes, int n_in,
                              void* d_out, int out_size, void* d_ws, size_t ws_size,
                              hipStream_t stream) {
  const float* x    = (const float*)d_in[0];
  const int*   eidx = (const int*)d_in[1];
  const int Nn = in_sizes[0] / 128;
  const int Ee = in_sizes[1] / 2;
  const int* src = eidx;
  const int* dst = eidx + Ee;

  const float* W1l = (const float*)d_in[3];  const float* b1l = (const float*)d_in[4];
  const float* W1r = (const float*)d_in[5];  const float* b1r = (const float*)d_in[6];
  const float* a1  = (const float*)d_in[7];  const float* bo1 = (const float*)d_in[8];
  const float* g1  = (const float*)d_in[9];  const float* be1 = (const float*)d_in[10];
  const float* W2l = (const float*)d_in[11]; const float* b2l = (const float*)d_in[12];
  const float* W2r = (const float*)d_in[13]; const float* b2r = (const float*)d_in[14];
  const float* a2  = (const float*)d_in[15]; const float* bo2 = (const float*)d_in[16];
  const float* g2  = (const float*)d_in[17]; const float* be2 = (const float*)d_in[18];
  const float* W3l = (const float*)d_in[19]; const float* b3l = (const float*)d_in[20];
  const float* W3r = (const float*)d_in[21]; const float* b3r = (const float*)d_in[22];
  const float* a3  = (const float*)d_in[23]; const float* bo3 = (const float*)d_in[24];
  const float* g3  = (const float*)d_in[25]; const float* be3 = (const float*)d_in[26];
  const float* linW = (const float*)d_in[27]; const float* linb = (const float*)d_in[28];

  char* ws = (char*)d_ws;
  unsigned short* xl   = (unsigned short*)ws; ws += (size_t)Nn * 256 * 2;
  unsigned short* xr   = (unsigned short*)ws; ws += (size_t)Nn * 256 * 2;
  unsigned short* Xb   = (unsigned short*)ws; ws += (size_t)Nn * 256 * 2;
  unsigned short* Wt1l = (unsigned short*)ws; ws += 256 * 128 * 2;
  unsigned short* Wt1r = (unsigned short*)ws; ws += 256 * 128 * 2;
  unsigned short* Wt2l = (unsigned short*)ws; ws += 256 * 256 * 2;
  unsigned short* Wt2r = (unsigned short*)ws; ws += 256 * 256 * 2;
  unsigned short* Wt3l = (unsigned short*)ws; ws += 64 * 256 * 2;
  unsigned short* Wt3r = (unsigned short*)ws; ws += 64 * 256 * 2;
  int*   deg    = (int*)ws;    ws += (size_t)Nn * 4;
  int*   rowptr = (int*)ws;    ws += (size_t)(Nn + 1) * 4;
  int*   bsum   = (int*)ws;    ws += 1024 * 4;
  int*   boff   = (int*)ws;    ws += 1024 * 4;
  int*   csr_src= (int*)ws;    ws += (size_t)Ee * 4;

  const int eblk = (Ee + 255) / 256;
  const int nblk = (Nn + 255) / 256;

  // ---------------- CSR build (by dst) + all weight conversions ----------------
  hipMemsetAsync(deg, 0, (size_t)Nn * 4, stream);
  hist_deg<<<eblk, 256, 0, stream>>>(dst, deg, Ee);
  wt_cvt_all<<<dim3(32, 6), 256, 0, stream>>>(W1l, W1r, W2l, W2r, W3l, W3r,
                                              Wt1l, Wt1r, Wt2l, Wt2r, Wt3l, Wt3r);
  scan_blk<<<nblk, 256, 0, stream>>>(deg, rowptr, bsum, Nn);
  scan_top<<<1, 1024, 0, stream>>>(bsum, boff, rowptr, nblk, Nn);
  scan_add<<<nblk, 256, 0, stream>>>(rowptr, boff, Nn);
  fill_csr<<<eblk, 256, 0, stream>>>(src, dst, rowptr, deg, csr_src, Ee);

  const int gdblk = (Nn + 63) / 64;

  // ---------------- layer 1: 128 -> 4x64 ----------------
  cvt_bf16<<<(Nn * 128 / 4 + 255) / 256, 256, 0, stream>>>(x, Xb, Nn * 128 / 4);
  gemm_dual<128><<<gdblk, 512, 0, stream>>>(Xb, Wt1l, Wt1r, b1l, b1r, xl, xr, Nn);
  gat_fused4<<<(Nn + 3) / 4, 256, 0, stream>>>(xl, xr, a1, rowptr, csr_src, bo1, g1, be1, Xb, Nn);

  // ---------------- layer 2: 256 -> 4x64 ----------------
  gemm_dual<256><<<gdblk, 512, 0, stream>>>(Xb, Wt2l, Wt2r, b2l, b2r, xl, xr, Nn);
  gat_fused4<<<(Nn + 3) / 4, 256, 0, stream>>>(xl, xr, a2, rowptr, csr_src, bo2, g2, be2, Xb, Nn);

  // ---------------- layer 3: 256 -> 1x64 + LN + final linear ----------------
  gemm_mfma2<256, 1><<<dim3((Nn + 63) / 64, 2), 256, 0, stream>>>(
      Xb, Wt3l, Wt3r, b3l, b3r, xl, xr, Nn, 64);
  gat1_lin<<<(Nn + 7) / 8, 512, 0, stream>>>(xl, xr, a3, rowptr, csr_src, bo3, g3, be3,
                                             linW, linb, (float*)d_out, Nn);
}